// Round 1
// baseline (263.504 us; speedup 1.0000x reference)
//
#include <hip/hip_runtime.h>
#include <cstddef>

// Problem constants
#define T_N 2048
#define D_N 512
#define H_N 8
#define M_N 4096   // B*T

// ---------------- trig table: tab[t][0..255]=cos, tab[t][256..511]=sin ----
__global__ __launch_bounds__(256) void trig_kernel(float* __restrict__ tab) {
  int idx = blockIdx.x * blockDim.x + threadIdx.x;   // T*256 threads
  int t = idx >> 8, f = idx & 255;
  // inv_freq = 10000^(-f/256) = exp2f(-f * log2(10000)/256)
  float invf = exp2f(-0.05190512648261503f * (float)f);
  float ang = (float)t * invf;
  float s, c;
  sincosf(ang, &s, &c);
  tab[t * 512 + f] = c;
  tab[t * 512 + 256 + f] = s;
}

// ---------------- generic f32 GEMM body -----------------------------------
// C[m0:m0+128, cn0:cn0+64] = A[m0:,:K] @ B[:, bn0:bn0+64]  (+bias)
#define BM 128
#define BN 64
#define BK 16

__device__ __forceinline__ void gemm_body(
    float as_t[BK][BM + 4], float bs[BK][BN],
    const float* __restrict__ A, int lda,
    const float* __restrict__ Bm, int ldb, int bn0,
    float* __restrict__ C, int ldc, int cn0,
    const float* __restrict__ bias, int m0, int K)
{
  const int tid = threadIdx.x;
  const int ty = tid >> 4, tx = tid & 15;
  const int ri = ty << 3, cj = tx << 2;   // 8x4 micro-tile
  float acc[8][4] = {};
  for (int k0 = 0; k0 < K; k0 += BK) {
    // stage A tile (128x16) transposed into as_t[k][m], scalar writes (2-way ok)
#pragma unroll
    for (int s = 0; s < 2; ++s) {
      int cc = tid * 2 + s;                 // float4 chunk id, [0,512)
      int row = cc >> 2, k4 = (cc & 3) << 2;
      const float4 v = *(const float4*)(A + (size_t)(m0 + row) * lda + k0 + k4);
      as_t[k4 + 0][row] = v.x;
      as_t[k4 + 1][row] = v.y;
      as_t[k4 + 2][row] = v.z;
      as_t[k4 + 3][row] = v.w;
    }
    // stage B tile (16x64), one float4 per thread
    {
      int row = tid >> 4, n4 = (tid & 15) << 2;
      *(float4*)(&bs[row][n4]) =
          *(const float4*)(Bm + (size_t)(k0 + row) * ldb + bn0 + n4);
    }
    __syncthreads();
#pragma unroll
    for (int kk = 0; kk < BK; ++kk) {
      const float4 a0 = *(const float4*)&as_t[kk][ri];
      const float4 a1 = *(const float4*)&as_t[kk][ri + 4];
      const float4 b4 = *(const float4*)&bs[kk][cj];
      const float av[8] = {a0.x, a0.y, a0.z, a0.w, a1.x, a1.y, a1.z, a1.w};
      const float bv[4] = {b4.x, b4.y, b4.z, b4.w};
#pragma unroll
      for (int r = 0; r < 8; ++r)
#pragma unroll
        for (int c = 0; c < 4; ++c)
          acc[r][c] += av[r] * bv[c];
    }
    __syncthreads();
  }
  float4 badd = make_float4(0.f, 0.f, 0.f, 0.f);
  if (bias) badd = *(const float4*)(bias + cn0 + cj);
#pragma unroll
  for (int r = 0; r < 8; ++r) {
    float4 o;
    o.x = acc[r][0] + badd.x;
    o.y = acc[r][1] + badd.y;
    o.z = acc[r][2] + badd.z;
    o.w = acc[r][3] + badd.w;
    *(float4*)(C + (size_t)(m0 + ri + r) * ldc + cn0 + cj) = o;
  }
}

// fused q + kv projection: n in [0,1536); n<512 -> Wq->qbuf, else Wkv->kvbuf
__global__ __launch_bounds__(256) void gemm_qkv(
    const float* __restrict__ x, const float* __restrict__ Wq,
    const float* __restrict__ Wkv, float* __restrict__ qbuf,
    float* __restrict__ kvbuf)
{
  __shared__ float as_t[BK][BM + 4];
  __shared__ float bs[BK][BN];
  const int m0 = blockIdx.y * BM;
  const int n0 = blockIdx.x * BN;
  if (n0 < 512) {
    gemm_body(as_t, bs, x, 512, Wq, 512, n0, qbuf, 512, n0, nullptr, m0, 512);
  } else {
    gemm_body(as_t, bs, x, 512, Wkv, 1024, n0 - 512, kvbuf, 1024, n0 - 512,
              nullptr, m0, 512);
  }
}

__global__ __launch_bounds__(256) void gemm_lin(
    const float* __restrict__ A, const float* __restrict__ Bm,
    const float* __restrict__ bias, float* __restrict__ C)
{
  __shared__ float as_t[BK][BM + 4];
  __shared__ float bs[BK][BN];
  const int m0 = blockIdx.y * BM;
  const int n0 = blockIdx.x * BN;
  gemm_body(as_t, bs, A, 512, Bm, 512, n0, C, 512, n0, bias, m0, 512);
}

// ---------------- RoPE in place on q (512-wide) and k half of kv ----------
// pair (c, c+256) across the FULL 512-dim vector (pre-head-split semantics)
__global__ __launch_bounds__(256) void rope_kernel(
    float* __restrict__ q, float* __restrict__ kv, const float* __restrict__ tab)
{
  int idx = blockIdx.x * blockDim.x + threadIdx.x;  // 2*M*64 threads
  int which = idx >> 18;                            // M*64 = 262144 = 2^18
  int r = idx & ((1 << 18) - 1);
  int m = r >> 6;
  int c4 = (r & 63) << 2;
  int t = m & (T_N - 1);
  float* base = which ? (kv + (size_t)m * 1024) : (q + (size_t)m * 512);
  float4 v1 = *(float4*)(base + c4);
  float4 v2 = *(float4*)(base + c4 + 256);
  const float4 ct = *(const float4*)(tab + (size_t)t * 512 + c4);
  const float4 st = *(const float4*)(tab + (size_t)t * 512 + 256 + c4);
  float4 o1, o2;
  o1.x = v1.x * ct.x - v2.x * st.x;  o2.x = v1.x * st.x + v2.x * ct.x;
  o1.y = v1.y * ct.y - v2.y * st.y;  o2.y = v1.y * st.y + v2.y * ct.y;
  o1.z = v1.z * ct.z - v2.z * st.z;  o2.z = v1.z * st.z + v2.z * ct.z;
  o1.w = v1.w * ct.w - v2.w * st.w;  o2.w = v1.w * st.w + v2.w * ct.w;
  *(float4*)(base + c4) = o1;
  *(float4*)(base + c4 + 256) = o2;
}

// ---------------- sliding-window attention --------------------------------
// One block per (b, h, 32-row t-tile). Keys staged for p in [t0-63, t0+32].
// Padded positions (p<0) are staged as ZEROS -> logit exactly 0 (matches
// reference's zero-padding inside softmax).
#define AT 32
#define KR 96

__global__ __launch_bounds__(256) void attn_kernel(
    const float* __restrict__ q, const float* __restrict__ kv,
    float* __restrict__ o)
{
  __shared__ float ks[KR][68];
  __shared__ float vs[KR][68];
  __shared__ float qp[AT][68];   // q rows, then reused for P (banded, compact)
  const int bid = blockIdx.x;
  const int tt = bid & 63;
  const int h  = (bid >> 6) & 7;
  const int b  = bid >> 9;
  const int t0 = tt * AT;
  const int tid = threadIdx.x;

  // stage q tile (32x64)
#pragma unroll
  for (int s = 0; s < 2; ++s) {
    int c = tid + s * 256;
    int row = c >> 4, d4 = (c & 15) << 2;
    *(float4*)&qp[row][d4] =
        *(const float4*)(q + ((size_t)(b * T_N + t0 + row)) * 512 + h * 64 + d4);
  }
  // stage k,v (96x64), zero outside [0,T)
#pragma unroll
  for (int s = 0; s < 6; ++s) {
    int c = tid + s * 256;
    int row = c >> 4, d4 = (c & 15) << 2;
    int p = t0 - 63 + row;
    float4 kx = make_float4(0.f, 0.f, 0.f, 0.f), vx = kx;
    if (p >= 0 && p < T_N) {
      const float* base = kv + ((size_t)(b * T_N + p)) * 1024 + h * 64 + d4;
      kx = *(const float4*)base;
      vx = *(const float4*)(base + 512);
    }
    *(float4*)&ks[row][d4] = kx;
    *(float4*)&vs[row][d4] = vx;
  }
  __syncthreads();

  const int ty = tid >> 4, tx = tid & 15;
  const int i0 = ty * 2;
  // S = Q @ K^T over staged rows; cols j = tx + 16*cjj (lane-consecutive)
  float acc[2][6] = {};
#pragma unroll
  for (int d4 = 0; d4 < 64; d4 += 4) {
    float4 qv0 = *(const float4*)&qp[i0][d4];
    float4 qv1 = *(const float4*)&qp[i0 + 1][d4];
#pragma unroll
    for (int cjj = 0; cjj < 6; ++cjj) {
      int j = tx + 16 * cjj;
      const float4 kk4 = *(const float4*)&ks[j][d4];
      acc[0][cjj] += qv0.x * kk4.x + qv0.y * kk4.y + qv0.z * kk4.z + qv0.w * kk4.w;
      acc[1][cjj] += qv1.x * kk4.x + qv1.y * kk4.y + qv1.z * kk4.z + qv1.w * kk4.w;
    }
  }
  __syncthreads();   // all reads of qp done before P overwrites it

  const float scale = 0.125f;   // DH^-0.5
#pragma unroll
  for (int r = 0; r < 2; ++r) {
    const int i = i0 + r;
    float mx = -1e30f;
#pragma unroll
    for (int cjj = 0; cjj < 6; ++cjj) {
      int w = tx + 16 * cjj - i;
      if (w >= 0 && w < 64) mx = fmaxf(mx, acc[r][cjj]);
    }
#pragma unroll
    for (int m = 1; m < 16; m <<= 1) mx = fmaxf(mx, __shfl_xor(mx, m));
    float sum = 0.f;
    float e[6];
#pragma unroll
    for (int cjj = 0; cjj < 6; ++cjj) {
      int w = tx + 16 * cjj - i;
      bool valid = (w >= 0 && w < 64);
      e[cjj] = valid ? expf((acc[r][cjj] - mx) * scale) : 0.f;
      sum += e[cjj];
    }
#pragma unroll
    for (int m = 1; m < 16; m <<= 1) sum += __shfl_xor(sum, m);
    const float inv = 1.f / sum;
#pragma unroll
    for (int cjj = 0; cjj < 6; ++cjj) {
      int w = tx + 16 * cjj - i;
      if (w >= 0 && w < 64) qp[i][w] = e[cjj] * inv;  // compact band store
    }
  }
  __syncthreads();

  // O = P @ V  (banded j-loop)
  const int dd = tx << 2;
  float acc2[2][4] = {};
  for (int j = i0; j <= i0 + 64; ++j) {
    const float4 vv = *(const float4*)&vs[j][dd];
#pragma unroll
    for (int r = 0; r < 2; ++r) {
      int w = j - i0 - r;
      if (w >= 0 && w < 64) {
        const float p = qp[i0 + r][w];
        acc2[r][0] += p * vv.x;
        acc2[r][1] += p * vv.y;
        acc2[r][2] += p * vv.z;
        acc2[r][3] += p * vv.w;
      }
    }
  }
#pragma unroll
  for (int r = 0; r < 2; ++r) {
    *(float4*)(o + ((size_t)(b * T_N + t0 + i0 + r)) * 512 + h * 64 + dd) =
        make_float4(acc2[r][0], acc2[r][1], acc2[r][2], acc2[r][3]);
  }
}

// ---------------- launch ---------------------------------------------------
extern "C" void kernel_launch(void* const* d_in, const int* in_sizes, int n_in,
                              void* d_out, int out_size, void* d_ws, size_t ws_size,
                              hipStream_t stream) {
  const float* x    = (const float*)d_in[0];
  const float* Wq   = (const float*)d_in[1];
  const float* Wkv  = (const float*)d_in[2];
  const float* Wlin = (const float*)d_in[3];
  const float* blin = (const float*)d_in[4];
  float* out = (float*)d_out;

  float* ws    = (float*)d_ws;
  float* qbuf  = ws;                                   // 4096*512
  float* kvbuf = qbuf + (size_t)M_N * 512;             // 4096*1024
  float* aobuf = kvbuf + (size_t)M_N * 1024;           // 4096*512
  float* tab   = aobuf + (size_t)M_N * 512;            // 2048*512

  trig_kernel<<<(T_N * 256) / 256, 256, 0, stream>>>(tab);
  gemm_qkv<<<dim3(1536 / BN, M_N / BM), 256, 0, stream>>>(x, Wq, Wkv, qbuf, kvbuf);
  rope_kernel<<<(2 * M_N * 64) / 256, 256, 0, stream>>>(qbuf, kvbuf, tab);
  attn_kernel<<<2 * H_N * (T_N / AT), 256, 0, stream>>>(qbuf, kvbuf, aobuf);
  gemm_lin<<<dim3(512 / BN, M_N / BM), 256, 0, stream>>>(aobuf, Wlin, blin, out);
}

// Round 2
// 222.112 us; speedup vs baseline: 1.1864x; 1.1864x over previous
//
#include <hip/hip_runtime.h>
#include <cstddef>
#include <cstdint>

// Problem constants
#define T_N 2048
#define D_N 512
#define H_N 8
#define M_N 4096   // B*T
#define KP  1536   // packed K: [hi | lo | hi] x 512

typedef __attribute__((ext_vector_type(8))) short bf16x8;
typedef __attribute__((ext_vector_type(4))) float f32x4;

__device__ __forceinline__ unsigned short f2bf(float f) {
  unsigned int u = __float_as_uint(f);
  unsigned int r = (u + 0x7FFFu + ((u >> 16) & 1u)) >> 16;   // RNE
  return (unsigned short)r;
}
__device__ __forceinline__ float bf2f(unsigned short h) {
  return __uint_as_float(((unsigned int)h) << 16);
}

#define GLOAD_LDS(g, l) __builtin_amdgcn_global_load_lds( \
    (const __attribute__((address_space(1))) unsigned int*)(g), \
    (__attribute__((address_space(3))) unsigned int*)(l), 16, 0, 0)

// ---------------- trig table: tab[t][0..255]=cos, tab[t][256..511]=sin ----
__global__ __launch_bounds__(256) void trig_kernel(float* __restrict__ tab) {
  int idx = blockIdx.x * blockDim.x + threadIdx.x;   // T*256 threads
  int t = idx >> 8, f = idx & 255;
  float invf = exp2f(-0.05190512648261503f * (float)f);  // 10000^(-f/256)
  float ang = (float)t * invf;
  float s, c;
  sincosf(ang, &s, &c);
  tab[t * 512 + f] = c;
  tab[t * 512 + 256 + f] = s;
}

// ---------------- pack activations: [M][512] f32 -> [M][1536] bf16 --------
// cols [0,512)=hi, [512,1024)=lo, [1024,1536)=hi (dup)
__global__ __launch_bounds__(256) void pack_a(const float* __restrict__ src,
                                              unsigned short* __restrict__ dst) {
  int idx = blockIdx.x * blockDim.x + threadIdx.x;   // M*128 threads
  int m = idx >> 7, k4 = (idx & 127) << 2;
  const float4 v = *(const float4*)(src + (size_t)m * 512 + k4);
  ushort4 h, l;
  h.x = f2bf(v.x); l.x = f2bf(v.x - bf2f(h.x));
  h.y = f2bf(v.y); l.y = f2bf(v.y - bf2f(h.y));
  h.z = f2bf(v.z); l.z = f2bf(v.z - bf2f(h.z));
  h.w = f2bf(v.w); l.w = f2bf(v.w - bf2f(h.w));
  unsigned short* row = dst + (size_t)m * KP + k4;
  *(ushort4*)(row)        = h;
  *(ushort4*)(row + 512)  = l;
  *(ushort4*)(row + 1024) = h;
}

// ---------------- pack weights transposed: W[512][N] -> out[N][1536] ------
// out row n: [0,512)=hi(W[:,n]), [512,1024)=hi, [1024,1536)=lo
__global__ __launch_bounds__(256) void pack_w(const float* __restrict__ W, int N,
                                              unsigned short* __restrict__ out) {
  __shared__ float tile[64][65];
  const int n0 = blockIdx.x * 64, k0 = blockIdx.y * 64;
  const int tid = threadIdx.x;
#pragma unroll
  for (int it = 0; it < 16; ++it) {
    int idx = tid + it * 256;
    int r = idx >> 6, c = idx & 63;
    tile[r][c] = W[(size_t)(k0 + r) * N + n0 + c];
  }
  __syncthreads();
#pragma unroll
  for (int it = 0; it < 16; ++it) {
    int idx = tid + it * 256;
    int n = idx >> 6, kk = idx & 63;
    float f = tile[kk][n];
    unsigned short h = f2bf(f);
    unsigned short l = f2bf(f - bf2f(h));
    unsigned short* row = out + (size_t)(n0 + n) * KP + k0 + kk;
    row[0]    = h;
    row[512]  = h;
    row[1024] = l;
  }
}

// ---------------- MFMA GEMM: C[M][ldc] = Ap[M][1536] @ Bp[N][1536]^T ------
// m97 structure: 128x128 tile, BK=64, 4 waves, global_load_lds width 16.
__global__ __launch_bounds__(256) void gemm_mfma(
    const unsigned short* __restrict__ Ap, const unsigned short* __restrict__ Bp,
    float* __restrict__ C, int ldc, const float* __restrict__ bias) {
  __shared__ __align__(16) unsigned short sA[128 * 64];
  __shared__ __align__(16) unsigned short sB[128 * 64];
  const int tid = threadIdx.x;
  const int wid = tid >> 6, lane = tid & 63;
  const int m0 = blockIdx.y * 128, n0 = blockIdx.x * 128;
  const int wm = (wid >> 1) * 64, wn = (wid & 1) * 64;
  f32x4 acc[4][4] = {};

  // staging: wave wid owns rows [wid*32, wid*32+32) of both tiles
  const int srow = wid * 32 + (lane >> 3);
  const int scol = (lane & 7) * 8;
  const unsigned short* ga = Ap + (size_t)(m0 + srow) * KP + scol;
  const unsigned short* gb = Bp + (size_t)(n0 + srow) * KP + scol;
  unsigned short* la = &sA[wid * 32 * 64];
  unsigned short* lb = &sB[wid * 32 * 64];

  for (int k0 = 0; k0 < KP; k0 += 64) {
#pragma unroll
    for (int i = 0; i < 4; ++i) {
      GLOAD_LDS(ga + (size_t)(i * 8) * KP + k0, la + i * 8 * 64);
      GLOAD_LDS(gb + (size_t)(i * 8) * KP + k0, lb + i * 8 * 64);
    }
    __syncthreads();
#pragma unroll
    for (int ks = 0; ks < 2; ++ks) {
      bf16x8 af[4], bfr[4];
#pragma unroll
      for (int i = 0; i < 4; ++i) {
        af[i]  = *(const bf16x8*)&sA[(wm + i * 16 + (lane & 15)) * 64 + ks * 32 + (lane >> 4) * 8];
        bfr[i] = *(const bf16x8*)&sB[(wn + i * 16 + (lane & 15)) * 64 + ks * 32 + (lane >> 4) * 8];
      }
#pragma unroll
      for (int i = 0; i < 4; ++i)
#pragma unroll
        for (int j = 0; j < 4; ++j)
          acc[i][j] = __builtin_amdgcn_mfma_f32_16x16x32_bf16(af[i], bfr[j], acc[i][j], 0, 0, 0);
    }
    __syncthreads();
  }
  // epilogue: C/D layout col=lane&15, row=(lane>>4)*4+r  [verified m89/m91]
  const int cn = n0 + wn + (lane & 15);
  const int rbase = m0 + wm + (lane >> 4) * 4;
#pragma unroll
  for (int j = 0; j < 4; ++j) {
    float badd = bias ? bias[cn + j * 16] : 0.f;
#pragma unroll
    for (int i = 0; i < 4; ++i)
#pragma unroll
      for (int r = 0; r < 4; ++r)
        C[(size_t)(rbase + i * 16 + r) * ldc + cn + j * 16] = acc[i][j][r] + badd;
  }
}

// ---------------- RoPE in place on qkvbuf [M][1536] -----------------------
// which=0: q cols [0,512); which=1: k cols [512,1024). pair (c, c+256).
__global__ __launch_bounds__(256) void rope_kernel(
    float* __restrict__ qkv, const float* __restrict__ tab) {
  int idx = blockIdx.x * blockDim.x + threadIdx.x;  // 2*M*64 threads
  int which = idx >> 18;                            // M*64 = 262144 = 2^18
  int r = idx & ((1 << 18) - 1);
  int m = r >> 6;
  int c4 = (r & 63) << 2;
  int t = m & (T_N - 1);
  float* base = qkv + (size_t)m * KP + (which ? 512 : 0);
  float4 v1 = *(float4*)(base + c4);
  float4 v2 = *(float4*)(base + c4 + 256);
  const float4 ct = *(const float4*)(tab + (size_t)t * 512 + c4);
  const float4 st = *(const float4*)(tab + (size_t)t * 512 + 256 + c4);
  float4 o1, o2;
  o1.x = v1.x * ct.x - v2.x * st.x;  o2.x = v1.x * st.x + v2.x * ct.x;
  o1.y = v1.y * ct.y - v2.y * st.y;  o2.y = v1.y * st.y + v2.y * ct.y;
  o1.z = v1.z * ct.z - v2.z * st.z;  o2.z = v1.z * st.z + v2.z * ct.z;
  o1.w = v1.w * ct.w - v2.w * st.w;  o2.w = v1.w * st.w + v2.w * ct.w;
  *(float4*)(base + c4) = o1;
  *(float4*)(base + c4 + 256) = o2;
}

// ---------------- sliding-window attention --------------------------------
#define AT 32
#define KR 96

__global__ __launch_bounds__(256) void attn_kernel(
    const float* __restrict__ qkv, float* __restrict__ o) {
  __shared__ float ks[KR][68];
  __shared__ float vs[KR][68];
  __shared__ float qp[AT][68];
  const int bid = blockIdx.x;
  const int tt = bid & 63;
  const int h  = (bid >> 6) & 7;
  const int b  = bid >> 9;
  const int t0 = tt * AT;
  const int tid = threadIdx.x;

#pragma unroll
  for (int s = 0; s < 2; ++s) {
    int c = tid + s * 256;
    int row = c >> 4, d4 = (c & 15) << 2;
    *(float4*)&qp[row][d4] =
        *(const float4*)(qkv + ((size_t)(b * T_N + t0 + row)) * KP + h * 64 + d4);
  }
#pragma unroll
  for (int s = 0; s < 6; ++s) {
    int c = tid + s * 256;
    int row = c >> 4, d4 = (c & 15) << 2;
    int p = t0 - 63 + row;
    float4 kx = make_float4(0.f, 0.f, 0.f, 0.f), vx = kx;
    if (p >= 0 && p < T_N) {
      const float* base = qkv + ((size_t)(b * T_N + p)) * KP + 512 + h * 64 + d4;
      kx = *(const float4*)base;
      vx = *(const float4*)(base + 512);
    }
    *(float4*)&ks[row][d4] = kx;
    *(float4*)&vs[row][d4] = vx;
  }
  __syncthreads();

  const int ty = tid >> 4, tx = tid & 15;
  const int i0 = ty * 2;
  float acc[2][6] = {};
#pragma unroll
  for (int d4 = 0; d4 < 64; d4 += 4) {
    float4 qv0 = *(const float4*)&qp[i0][d4];
    float4 qv1 = *(const float4*)&qp[i0 + 1][d4];
#pragma unroll
    for (int cjj = 0; cjj < 6; ++cjj) {
      int j = tx + 16 * cjj;
      const float4 kk4 = *(const float4*)&ks[j][d4];
      acc[0][cjj] += qv0.x * kk4.x + qv0.y * kk4.y + qv0.z * kk4.z + qv0.w * kk4.w;
      acc[1][cjj] += qv1.x * kk4.x + qv1.y * kk4.y + qv1.z * kk4.z + qv1.w * kk4.w;
    }
  }
  __syncthreads();

  const float scale = 0.125f;
#pragma unroll
  for (int r = 0; r < 2; ++r) {
    const int i = i0 + r;
    float mx = -1e30f;
#pragma unroll
    for (int cjj = 0; cjj < 6; ++cjj) {
      int w = tx + 16 * cjj - i;
      if (w >= 0 && w < 64) mx = fmaxf(mx, acc[r][cjj]);
    }
#pragma unroll
    for (int m = 1; m < 16; m <<= 1) mx = fmaxf(mx, __shfl_xor(mx, m));
    float sum = 0.f;
    float e[6];
#pragma unroll
    for (int cjj = 0; cjj < 6; ++cjj) {
      int w = tx + 16 * cjj - i;
      bool valid = (w >= 0 && w < 64);
      e[cjj] = valid ? expf((acc[r][cjj] - mx) * scale) : 0.f;
      sum += e[cjj];
    }
#pragma unroll
    for (int m = 1; m < 16; m <<= 1) sum += __shfl_xor(sum, m);
    const float inv = 1.f / sum;
#pragma unroll
    for (int cjj = 0; cjj < 6; ++cjj) {
      int w = tx + 16 * cjj - i;
      if (w >= 0 && w < 64) qp[i][w] = e[cjj] * inv;
    }
  }
  __syncthreads();

  const int dd = tx << 2;
  float acc2[2][4] = {};
  for (int j = i0; j <= i0 + 64; ++j) {
    const float4 vv = *(const float4*)&vs[j][dd];
#pragma unroll
    for (int r = 0; r < 2; ++r) {
      int w = j - i0 - r;
      if (w >= 0 && w < 64) {
        const float p = qp[i0 + r][w];
        acc2[r][0] += p * vv.x;
        acc2[r][1] += p * vv.y;
        acc2[r][2] += p * vv.z;
        acc2[r][3] += p * vv.w;
      }
    }
  }
#pragma unroll
  for (int r = 0; r < 2; ++r) {
    *(float4*)(o + ((size_t)(b * T_N + t0 + i0 + r)) * 512 + h * 64 + dd) =
        make_float4(acc2[r][0], acc2[r][1], acc2[r][2], acc2[r][3]);
  }
}

// ---------------- launch ---------------------------------------------------
extern "C" void kernel_launch(void* const* d_in, const int* in_sizes, int n_in,
                              void* d_out, int out_size, void* d_ws, size_t ws_size,
                              hipStream_t stream) {
  const float* x    = (const float*)d_in[0];
  const float* Wq   = (const float*)d_in[1];
  const float* Wkv  = (const float*)d_in[2];
  const float* Wlin = (const float*)d_in[3];
  const float* blin = (const float*)d_in[4];
  float* out = (float*)d_out;

  char* ws = (char*)d_ws;
  // byte offsets (see journal): total 56.6 MB
  float*          qkvbuf = (float*)(ws);                         // 4096*1536*4 = 25.17MB
  float*          aobuf  = (float*)(ws + 25165824);              // 8.39MB
  float*          tab    = (float*)(ws + 33554432);              // 4.19MB
  unsigned short* Axp    = (unsigned short*)(ws + 37748736);     // 12.58MB
  unsigned short* Wcatp  = (unsigned short*)(ws + 50331648);     // 4.72MB
  unsigned short* Wlinp  = (unsigned short*)(ws + 55050240);     // 1.57MB
  unsigned short* Aaop   = (unsigned short*)(ws);                // overlay qkvbuf (dead after attn)

  trig_kernel<<<T_N, 256, 0, stream>>>(tab);
  pack_a<<<(M_N * 128) / 256, 256, 0, stream>>>(x, Axp);
  pack_w<<<dim3(8, 8),  256, 0, stream>>>(Wq,   512, Wcatp);
  pack_w<<<dim3(16, 8), 256, 0, stream>>>(Wkv, 1024, Wcatp + (size_t)512 * KP);
  pack_w<<<dim3(8, 8),  256, 0, stream>>>(Wlin, 512, Wlinp);
  gemm_mfma<<<dim3(12, 32), 256, 0, stream>>>(Axp, Wcatp, qkvbuf, KP, nullptr);
  rope_kernel<<<(2 * M_N * 64) / 256, 256, 0, stream>>>(qkvbuf, tab);
  attn_kernel<<<2 * H_N * (T_N / AT), 256, 0, stream>>>(qkvbuf, aobuf);
  pack_a<<<(M_N * 128) / 256, 256, 0, stream>>>(aobuf, Aaop);
  gemm_mfma<<<dim3(4, 32), 256, 0, stream>>>(Aaop, Wlinp, out, 512, blin);
}

// Round 4
// 169.107 us; speedup vs baseline: 1.5582x; 1.3134x over previous
//
#include <hip/hip_runtime.h>
#include <cstddef>

// Problem constants
#define T_N 2048
#define D_N 512
#define H_N 8
#define M_N 4096   // B*T
#define KP  1536   // packed K: [hi | lo | hi] x 512

typedef __attribute__((ext_vector_type(8))) short bf16x8;
typedef __attribute__((ext_vector_type(4))) float f32x4;
typedef _Float16 f16x8 __attribute__((ext_vector_type(8)));
typedef __attribute__((ext_vector_type(8))) unsigned short u16x8;

__device__ __forceinline__ unsigned short f2bf(float f) {
  unsigned int u = __float_as_uint(f);
  unsigned int r = (u + 0x7FFFu + ((u >> 16) & 1u)) >> 16;   // RNE
  return (unsigned short)r;
}
__device__ __forceinline__ float bf2f(unsigned short h) {
  return __uint_as_float(((unsigned int)h) << 16);
}

#define GLOAD_LDS(g, l) __builtin_amdgcn_global_load_lds( \
    (const __attribute__((address_space(1))) unsigned int*)(g), \
    (__attribute__((address_space(3))) unsigned int*)(l), 16, 0, 0)

// ---------------- trig table: tab[t][0..255]=cos, tab[t][256..511]=sin ----
__global__ __launch_bounds__(256) void trig_kernel(float* __restrict__ tab) {
  int idx = blockIdx.x * blockDim.x + threadIdx.x;   // T*256 threads
  int t = idx >> 8, f = idx & 255;
  float invf = exp2f(-0.05190512648261503f * (float)f);  // 10000^(-f/256)
  float ang = (float)t * invf;
  float s, c;
  sincosf(ang, &s, &c);
  tab[t * 512 + f] = c;
  tab[t * 512 + 256 + f] = s;
}

// ---------------- fused packing: x -> Axp, and Wq/Wkv/Wlin transposed -----
__global__ __launch_bounds__(256) void pack_all(
    const float* __restrict__ x, const float* __restrict__ Wq,
    const float* __restrict__ Wkv, const float* __restrict__ Wlin,
    unsigned short* __restrict__ Axp, unsigned short* __restrict__ Wcatp,
    unsigned short* __restrict__ Wlinp) {
  __shared__ float tile[64][65];
  int bid = blockIdx.x;
  const int tid = threadIdx.x;
  if (bid < 2048) {
    // pack activations: [M][512] f32 -> [M][1536] bf16 hi|lo|hi
    int idx = bid * 256 + tid;          // M*128 ids
    int m = idx >> 7, k4 = (idx & 127) << 2;
    const float4 v = *(const float4*)(x + (size_t)m * 512 + k4);
    ushort4 h, l;
    h.x = f2bf(v.x); l.x = f2bf(v.x - bf2f(h.x));
    h.y = f2bf(v.y); l.y = f2bf(v.y - bf2f(h.y));
    h.z = f2bf(v.z); l.z = f2bf(v.z - bf2f(h.z));
    h.w = f2bf(v.w); l.w = f2bf(v.w - bf2f(h.w));
    unsigned short* row = Axp + (size_t)m * KP + k4;
    *(ushort4*)(row)        = h;
    *(ushort4*)(row + 512)  = l;
    *(ushort4*)(row + 1024) = h;
    return;
  }
  bid -= 2048;
  const float* W; int N; unsigned short* out; int bx, by;
  if (bid < 64)       { W = Wq;   N = 512;  out = Wcatp;                      bx = bid & 7;  by = bid >> 3; }
  else if (bid < 192) { bid -= 64;  W = Wkv; N = 1024; out = Wcatp + (size_t)512 * KP; bx = bid & 15; by = bid >> 4; }
  else                { bid -= 192; W = Wlin; N = 512; out = Wlinp;           bx = bid & 7;  by = bid >> 3; }
  const int n0 = bx * 64, k0 = by * 64;
#pragma unroll
  for (int it = 0; it < 16; ++it) {
    int idx = tid + it * 256;
    int r = idx >> 6, c = idx & 63;
    tile[r][c] = W[(size_t)(k0 + r) * N + n0 + c];
  }
  __syncthreads();
#pragma unroll
  for (int it = 0; it < 16; ++it) {
    int idx = tid + it * 256;
    int n = idx >> 6, kk = idx & 63;
    float f = tile[kk][n];
    unsigned short h = f2bf(f);
    unsigned short l = f2bf(f - bf2f(h));
    unsigned short* row = out + (size_t)(n0 + n) * KP + k0 + kk;
    row[0]    = h;   // hi
    row[512]  = h;   // hi (pairs with A lo)
    row[1024] = l;   // lo (pairs with A hi)
  }
}

// ---------------- MFMA GEMM: C[M][ldc] = Ap[M][1536] @ Bp[N][1536]^T ------
__global__ __launch_bounds__(256) void gemm_mfma(
    const unsigned short* __restrict__ Ap, const unsigned short* __restrict__ Bp,
    float* __restrict__ C, int ldc, const float* __restrict__ bias) {
  __shared__ __align__(16) unsigned short sA[128 * 64];
  __shared__ __align__(16) unsigned short sB[128 * 64];
  const int tid = threadIdx.x;
  const int wid = tid >> 6, lane = tid & 63;
  const int m0 = blockIdx.y * 128, n0 = blockIdx.x * 128;
  const int wm = (wid >> 1) * 64, wn = (wid & 1) * 64;
  f32x4 acc[4][4] = {};

  const int srow = wid * 32 + (lane >> 3);
  const int scol = (lane & 7) * 8;
  const unsigned short* ga = Ap + (size_t)(m0 + srow) * KP + scol;
  const unsigned short* gb = Bp + (size_t)(n0 + srow) * KP + scol;
  unsigned short* la = &sA[wid * 32 * 64];
  unsigned short* lb = &sB[wid * 32 * 64];

  for (int k0 = 0; k0 < KP; k0 += 64) {
#pragma unroll
    for (int i = 0; i < 4; ++i) {
      GLOAD_LDS(ga + (size_t)(i * 8) * KP + k0, la + i * 8 * 64);
      GLOAD_LDS(gb + (size_t)(i * 8) * KP + k0, lb + i * 8 * 64);
    }
    __syncthreads();
#pragma unroll
    for (int ks = 0; ks < 2; ++ks) {
      bf16x8 af[4], bfr[4];
#pragma unroll
      for (int i = 0; i < 4; ++i) {
        af[i]  = *(const bf16x8*)&sA[(wm + i * 16 + (lane & 15)) * 64 + ks * 32 + (lane >> 4) * 8];
        bfr[i] = *(const bf16x8*)&sB[(wn + i * 16 + (lane & 15)) * 64 + ks * 32 + (lane >> 4) * 8];
      }
#pragma unroll
      for (int i = 0; i < 4; ++i)
#pragma unroll
        for (int j = 0; j < 4; ++j)
          acc[i][j] = __builtin_amdgcn_mfma_f32_16x16x32_bf16(af[i], bfr[j], acc[i][j], 0, 0, 0);
    }
    __syncthreads();
  }
  const int cn = n0 + wn + (lane & 15);
  const int rbase = m0 + wm + (lane >> 4) * 4;
#pragma unroll
  for (int j = 0; j < 4; ++j) {
    float badd = bias ? bias[cn + j * 16] : 0.f;
#pragma unroll
    for (int i = 0; i < 4; ++i)
#pragma unroll
      for (int r = 0; r < 4; ++r)
        C[(size_t)(rbase + i * 16 + r) * ldc + cn + j * 16] = acc[i][j][r] + badd;
  }
}

// ---------------- fused attention: rope + QK^T + softmax + PV + pack ------
// block = 256 thr (4 waves), one (b, h, 32-row tile) per block.
// LDS (f16 units): K[96][72] @0 | Q[32][72] @6912 | VT[64][104] @9216 |
//                  P[32][104] @15872 ; OutHi[32][72]@0, OutLo@2304 (overlay K)
#define RQ 72
#define RK 72
#define RV 104
#define RP 104
#define RO 72

__global__ __launch_bounds__(256, 4) void attn_fused(
    const float* __restrict__ qkv, const float* __restrict__ tab,
    unsigned short* __restrict__ Aout) {
  __shared__ __align__(16) _Float16 sm[19200];
  __shared__ float pm[2][32];
  __shared__ float ps[2][32];
  _Float16* Ks  = sm;
  _Float16* Qs  = sm + 6912;
  _Float16* VTs = sm + 9216;
  _Float16* Ps  = sm + 15872;
  unsigned short* OH = (unsigned short*)sm;          // bf16 hi plane
  unsigned short* OL = (unsigned short*)(sm + 2304); // bf16 lo plane

  const int wgid = blockIdx.x;
  const int orig = (wgid & 7) * 128 + (wgid >> 3);   // XCD swizzle (1024 = 8*128)
  const int tile = orig & 63;
  const int h = (orig >> 6) & 7;
  const int b = orig >> 9;
  const int t0 = tile * 32;
  const int tid = threadIdx.x;
  const int ph = h ^ 4;
  const float spm = (h < 4) ? -1.f : 1.f;
  const int fb = (h & 3) * 64;
  const size_t bT = (size_t)b * T_N;

  // ---- stage Q (32 rows x 64) with fused RoPE
  {
    int i = tid >> 3, d8 = (tid & 7) * 8;
    int t = t0 + i;
    const float* rowp = qkv + (bT + t) * KP;
    float A[8], Bv[8], Cc[8], Ss[8];
    *(float4*)(A)      = *(const float4*)(rowp + h * 64 + d8);
    *(float4*)(A + 4)  = *(const float4*)(rowp + h * 64 + d8 + 4);
    *(float4*)(Bv)     = *(const float4*)(rowp + ph * 64 + d8);
    *(float4*)(Bv + 4) = *(const float4*)(rowp + ph * 64 + d8 + 4);
    const float* tr = tab + (size_t)t * 512 + fb + d8;
    *(float4*)(Cc)     = *(const float4*)(tr);
    *(float4*)(Cc + 4) = *(const float4*)(tr + 4);
    *(float4*)(Ss)     = *(const float4*)(tr + 256);
    *(float4*)(Ss + 4) = *(const float4*)(tr + 260);
    f16x8 o;
#pragma unroll
    for (int e = 0; e < 8; ++e) o[e] = (_Float16)(A[e] * Cc[e] + spm * Bv[e] * Ss[e]);
    *(f16x8*)(Qs + i * RQ + d8) = o;
  }
  // ---- stage K (96 rows x 64) with fused RoPE, zero outside [0,T)
#pragma unroll
  for (int itn = 0; itn < 3; ++itn) {
    int c = tid + itn * 256;
    int jr = c >> 3, d8 = (c & 7) * 8;
    int p = t0 - 63 + jr;
    f16x8 o = {};
    if (p >= 0 && p < T_N) {
      const float* rowp = qkv + (bT + p) * KP + 512;
      float A[8], Bv[8], Cc[8], Ss[8];
      *(float4*)(A)      = *(const float4*)(rowp + h * 64 + d8);
      *(float4*)(A + 4)  = *(const float4*)(rowp + h * 64 + d8 + 4);
      *(float4*)(Bv)     = *(const float4*)(rowp + ph * 64 + d8);
      *(float4*)(Bv + 4) = *(const float4*)(rowp + ph * 64 + d8 + 4);
      const float* tr = tab + (size_t)p * 512 + fb + d8;
      *(float4*)(Cc)     = *(const float4*)(tr);
      *(float4*)(Cc + 4) = *(const float4*)(tr + 4);
      *(float4*)(Ss)     = *(const float4*)(tr + 256);
      *(float4*)(Ss + 4) = *(const float4*)(tr + 260);
#pragma unroll
      for (int e = 0; e < 8; ++e) o[e] = (_Float16)(A[e] * Cc[e] + spm * Bv[e] * Ss[e]);
    }
    *(f16x8*)(Ks + jr * RK + d8) = o;
  }
  // ---- stage V transposed: VT[d][j], coalesced column reads
#pragma unroll
  for (int itn = 0; itn < 3; ++itn) {
    int c = tid + itn * 256;
    int d = c & 63, jr8 = (c >> 6) * 8;
    const float* colp = qkv + bT * KP + 1024 + (size_t)h * 64 + d;
    f16x8 o = {};
#pragma unroll
    for (int e = 0; e < 8; ++e) {
      int p = t0 - 63 + jr8 + e;
      if (p >= 0 && p < T_N) o[e] = (_Float16)colp[(size_t)p * KP];
    }
    *(f16x8*)(VTs + d * RV + jr8) = o;
  }
  __syncthreads();

  // ---- wave roles: it = query half, jh = key half (j in [48*jh, 48*jh+48))
  const int lane = tid & 63;
  const int il = lane & 15, g = lane >> 4;
  const int w = tid >> 6;
  const int it = w & 1, jh = w >> 1;
  const int i_q = 16 * it + il;

  // QK^T (swapped): sacc[jt][r] = S^T[j][i], j = 16*(3jh+jt)+4g+r, i = i_q
  f32x4 sacc[3] = {};
  {
    f16x8 qf0 = *(const f16x8*)(Qs + i_q * RQ + 8 * g);
    f16x8 qf1 = *(const f16x8*)(Qs + i_q * RQ + 32 + 8 * g);
#pragma unroll
    for (int jt = 0; jt < 3; ++jt) {
      int jrow = 16 * (3 * jh + jt) + il;
      f16x8 a0 = *(const f16x8*)(Ks + jrow * RK + 8 * g);
      f16x8 a1 = *(const f16x8*)(Ks + jrow * RK + 32 + 8 * g);
      sacc[jt] = __builtin_amdgcn_mfma_f32_16x16x32_f16(a0, qf0, sacc[jt], 0, 0, 0);
      sacc[jt] = __builtin_amdgcn_mfma_f32_16x16x32_f16(a1, qf1, sacc[jt], 0, 0, 0);
    }
  }
  // ---- softmax: cross-wave (2 j-halves) via LDS partials
  float mx = -3e38f;
#pragma unroll
  for (int jt = 0; jt < 3; ++jt)
#pragma unroll
    for (int r = 0; r < 4; ++r) {
      int j = 16 * (3 * jh + jt) + 4 * g + r;
      int wv = j - i_q;
      if (wv >= 0 && wv < 64) mx = fmaxf(mx, sacc[jt][r]);
    }
  mx = fmaxf(mx, __shfl_xor(mx, 16));
  mx = fmaxf(mx, __shfl_xor(mx, 32));
  if (g == 0) pm[jh][i_q] = mx;
  __syncthreads();
  {
    const float m = fmaxf(pm[0][i_q], pm[1][i_q]);
    float sum = 0.f;
#pragma unroll
    for (int jt = 0; jt < 3; ++jt)
#pragma unroll
      for (int r = 0; r < 4; ++r) {
        int j = 16 * (3 * jh + jt) + 4 * g + r;
        int wv = j - i_q;
        float ex = 0.f;
        if (wv >= 0 && wv < 64) {
          ex = exp2f((sacc[jt][r] - m) * 0.18033688011112042f);  // *0.125*log2(e)
          sum += ex;
        }
        Ps[i_q * RP + j] = (_Float16)ex;
      }
    sum += __shfl_xor(sum, 16);
    sum += __shfl_xor(sum, 32);
    if (g == 0) ps[jh][i_q] = sum;
  }
  __syncthreads();

  // ---- PV: out[i][d] = sum_j P[i][j] * VT[d][j]; wave does (it, dt={jh,jh+2})
  f32x4 oacc[2] = {};
#pragma unroll
  for (int ks = 0; ks < 3; ++ks) {
    f16x8 pf = *(const f16x8*)(Ps + i_q * RP + 32 * ks + 8 * g);
#pragma unroll
    for (int q2 = 0; q2 < 2; ++q2) {
      int dt = jh + 2 * q2;
      f16x8 vf = *(const f16x8*)(VTs + (16 * dt + il) * RV + 32 * ks + 8 * g);
      oacc[q2] = __builtin_amdgcn_mfma_f32_16x16x32_f16(pf, vf, oacc[q2], 0, 0, 0);
    }
  }
  // ---- epilogue: normalize, split bf16 hi/lo into LDS (overlay on K)
#pragma unroll
  for (int r = 0; r < 4; ++r) {
    int i = 16 * it + 4 * g + r;
    float inv = 1.f / (ps[0][i] + ps[1][i]);
#pragma unroll
    for (int q2 = 0; q2 < 2; ++q2) {
      int d = 16 * (jh + 2 * q2) + il;
      float val = oacc[q2][r] * inv;
      unsigned short hi = f2bf(val);
      unsigned short lo = f2bf(val - bf2f(hi));
      OH[i * RO + d] = hi;
      OL[i * RO + d] = lo;
    }
  }
  __syncthreads();
  // ---- final coalesced packed write: Aout[m][hi|lo|hi]
  {
    int i = tid >> 3, d8 = (tid & 7) * 8;
    u16x8 hi = *(const u16x8*)(OH + i * RO + d8);
    u16x8 lo = *(const u16x8*)(OL + i * RO + d8);
    unsigned short* rowp = Aout + (bT + t0 + i) * KP;
    *(u16x8*)(rowp + h * 64 + d8)        = hi;
    *(u16x8*)(rowp + 512 + h * 64 + d8)  = lo;
    *(u16x8*)(rowp + 1024 + h * 64 + d8) = hi;
  }
}

// ---------------- launch ---------------------------------------------------
extern "C" void kernel_launch(void* const* d_in, const int* in_sizes, int n_in,
                              void* d_out, int out_size, void* d_ws, size_t ws_size,
                              hipStream_t stream) {
  const float* x    = (const float*)d_in[0];
  const float* Wq   = (const float*)d_in[1];
  const float* Wkv  = (const float*)d_in[2];
  const float* Wlin = (const float*)d_in[3];
  const float* blin = (const float*)d_in[4];
  float* out = (float*)d_out;

  char* ws = (char*)d_ws;
  float*          qkvbuf = (float*)(ws);                       // 25.17 MB
  float*          tab    = (float*)(ws + 25165824);            //  4.19 MB
  unsigned short* Axp    = (unsigned short*)(ws + 29360128);   // 12.58 MB
  unsigned short* Wcatp  = (unsigned short*)(ws + 41943040);   //  4.72 MB
  unsigned short* Wlinp  = (unsigned short*)(ws + 46661632);   //  1.57 MB
  unsigned short* Aaop   = Axp;  // reuse: Axp dead after gemm_qkv

  trig_kernel<<<T_N, 256, 0, stream>>>(tab);
  pack_all<<<2304, 256, 0, stream>>>(x, Wq, Wkv, Wlin, Axp, Wcatp, Wlinp);
  gemm_mfma<<<dim3(12, 32), 256, 0, stream>>>(Axp, Wcatp, qkvbuf, KP, nullptr);
  attn_fused<<<1024, 256, 0, stream>>>(qkvbuf, tab, Aaop);
  gemm_mfma<<<dim3(4, 32), 256, 0, stream>>>(Aaop, Wlinp, out, 512, blin);
}

// Round 5
// 116.196 us; speedup vs baseline: 2.2678x; 1.4554x over previous
//
#include <hip/hip_runtime.h>
#include <cstddef>

// Problem constants
#define T_N 2048
#define D_N 512
#define H_N 8
#define M_N 4096   // B*T
#define KP  512    // GEMM K (fp16 single-term)

typedef __attribute__((ext_vector_type(4))) float f32x4;
typedef _Float16 f16x8 __attribute__((ext_vector_type(8)));
typedef _Float16 f16x4 __attribute__((ext_vector_type(4)));

#define GLOAD_LDS(g, l) __builtin_amdgcn_global_load_lds( \
    (const __attribute__((address_space(1))) unsigned int*)(g), \
    (__attribute__((address_space(3))) unsigned int*)(l), 16, 0, 0)

// ---------------- trig table: tab[t][0..255]=cos, tab[t][256..511]=sin ----
__global__ __launch_bounds__(256) void trig_kernel(float* __restrict__ tab) {
  int idx = blockIdx.x * blockDim.x + threadIdx.x;   // T*256 threads
  int t = idx >> 8, f = idx & 255;
  float invf = exp2f(-0.05190512648261503f * (float)f);  // 10000^(-f/256)
  float ang = (float)t * invf;
  float s, c;
  sincosf(ang, &s, &c);
  tab[t * 512 + f] = c;
  tab[t * 512 + 256 + f] = s;
}

// ---------------- fused packing: x -> f16, W's -> transposed f16 ----------
__global__ __launch_bounds__(256) void pack_all(
    const float* __restrict__ x, const float* __restrict__ Wq,
    const float* __restrict__ Wkv, const float* __restrict__ Wlin,
    _Float16* __restrict__ Axp, _Float16* __restrict__ Wcatp,
    _Float16* __restrict__ Wlinp) {
  __shared__ float tile[64][65];
  int bid = blockIdx.x;
  const int tid = threadIdx.x;
  if (bid < 1024) {
    // x [M][512] f32 -> Axp [M][512] f16
    int idx = bid * 256 + tid;           // M*64 ids
    int m = idx >> 6, k8 = (idx & 63) << 3;
    const float* src = x + (size_t)m * 512 + k8;
    const float4 a = *(const float4*)src;
    const float4 b = *(const float4*)(src + 4);
    f16x8 o;
    o[0] = (_Float16)a.x; o[1] = (_Float16)a.y; o[2] = (_Float16)a.z; o[3] = (_Float16)a.w;
    o[4] = (_Float16)b.x; o[5] = (_Float16)b.y; o[6] = (_Float16)b.z; o[7] = (_Float16)b.w;
    *(f16x8*)(Axp + (size_t)m * 512 + k8) = o;
    return;
  }
  bid -= 1024;
  const float* W; int N; _Float16* out; int bx, by;
  if (bid < 64)       { W = Wq;   N = 512;  out = Wcatp;                        bx = bid & 7;  by = bid >> 3; }
  else if (bid < 192) { bid -= 64;  W = Wkv; N = 1024; out = Wcatp + (size_t)512 * KP; bx = bid & 15; by = bid >> 4; }
  else                { bid -= 192; W = Wlin; N = 512; out = Wlinp;             bx = bid & 7;  by = bid >> 3; }
  const int n0 = bx * 64, k0 = by * 64;
#pragma unroll
  for (int it = 0; it < 16; ++it) {
    int idx = tid + it * 256;
    int r = idx >> 6, c = idx & 63;
    tile[r][c] = W[(size_t)(k0 + r) * N + n0 + c];
  }
  __syncthreads();
#pragma unroll
  for (int it = 0; it < 16; ++it) {
    int idx = tid + it * 256;
    int n = idx >> 6, kk = idx & 63;
    out[(size_t)(n0 + n) * KP + k0 + kk] = (_Float16)tile[kk][n];
  }
}

// ---------------- MFMA GEMM (fp16): C[M][ldc] = Ap[M][512] @ Bp[N][512]^T -
__global__ __launch_bounds__(256) void gemm_mfma(
    const _Float16* __restrict__ Ap, const _Float16* __restrict__ Bp,
    float* __restrict__ C, int ldc, const float* __restrict__ bias) {
  __shared__ __align__(16) _Float16 sA[128 * 64];
  __shared__ __align__(16) _Float16 sB[128 * 64];
  const int tid = threadIdx.x;
  const int wid = tid >> 6, lane = tid & 63;
  const int m0 = blockIdx.y * 128, n0 = blockIdx.x * 128;
  const int wm = (wid >> 1) * 64, wn = (wid & 1) * 64;
  f32x4 acc[4][4] = {};

  const int srow = wid * 32 + (lane >> 3);
  const int scol = (lane & 7) * 8;
  const _Float16* ga = Ap + (size_t)(m0 + srow) * KP + scol;
  const _Float16* gb = Bp + (size_t)(n0 + srow) * KP + scol;
  _Float16* la = &sA[wid * 32 * 64];
  _Float16* lb = &sB[wid * 32 * 64];

  for (int k0 = 0; k0 < KP; k0 += 64) {
#pragma unroll
    for (int i = 0; i < 4; ++i) {
      GLOAD_LDS(ga + (size_t)(i * 8) * KP + k0, la + i * 8 * 64);
      GLOAD_LDS(gb + (size_t)(i * 8) * KP + k0, lb + i * 8 * 64);
    }
    __syncthreads();
#pragma unroll
    for (int ks = 0; ks < 2; ++ks) {
      f16x8 af[4], bfr[4];
#pragma unroll
      for (int i = 0; i < 4; ++i) {
        af[i]  = *(const f16x8*)&sA[(wm + i * 16 + (lane & 15)) * 64 + ks * 32 + (lane >> 4) * 8];
        bfr[i] = *(const f16x8*)&sB[(wn + i * 16 + (lane & 15)) * 64 + ks * 32 + (lane >> 4) * 8];
      }
#pragma unroll
      for (int i = 0; i < 4; ++i)
#pragma unroll
        for (int j = 0; j < 4; ++j)
          acc[i][j] = __builtin_amdgcn_mfma_f32_16x16x32_f16(af[i], bfr[j], acc[i][j], 0, 0, 0);
    }
    __syncthreads();
  }
  // C/D layout: col=lane&15, row=(lane>>4)*4+r  [verified]
  const int cn = n0 + wn + (lane & 15);
  const int rbase = m0 + wm + (lane >> 4) * 4;
#pragma unroll
  for (int j = 0; j < 4; ++j) {
    float badd = bias ? bias[cn + j * 16] : 0.f;
#pragma unroll
    for (int i = 0; i < 4; ++i)
#pragma unroll
      for (int r = 0; r < 4; ++r)
        C[(size_t)(rbase + i * 16 + r) * ldc + cn + j * 16] = acc[i][j][r] + badd;
  }
}

// ---------------- rope + layout prep --------------------------------------
// part A (2048 blocks): rope q,k from qkvbuf f32 -> Qh/Kh f16 [b][h][t][64]
// part B (512 blocks): v transpose -> Vh f16 [b][h][64][2048]
__global__ __launch_bounds__(256) void rope_pack(
    const float* __restrict__ qkv, const float* __restrict__ tab,
    _Float16* __restrict__ Qh, _Float16* __restrict__ Kh,
    _Float16* __restrict__ Vh) {
  int bid = blockIdx.x;
  const int tid = threadIdx.x;
  if (bid < 2048) {
    int idx = bid * 256 + tid;          // 2*M*64 ids
    int which = idx >> 18;              // 0=q, 1=k
    int r = idx & ((1 << 18) - 1);
    int m = r >> 6;
    int c4 = (r & 63) << 2;
    int t = m & (T_N - 1);
    int b = m >> 11;
    const float* base = qkv + (size_t)m * 1536 + (which ? 512 : 0);
    const float4 v1 = *(const float4*)(base + c4);
    const float4 v2 = *(const float4*)(base + c4 + 256);
    const float4 ct = *(const float4*)(tab + (size_t)t * 512 + c4);
    const float4 st = *(const float4*)(tab + (size_t)t * 512 + 256 + c4);
    f16x4 o1, o2;
    o1[0] = (_Float16)(v1.x * ct.x - v2.x * st.x);  o2[0] = (_Float16)(v1.x * st.x + v2.x * ct.x);
    o1[1] = (_Float16)(v1.y * ct.y - v2.y * st.y);  o2[1] = (_Float16)(v1.y * st.y + v2.y * ct.y);
    o1[2] = (_Float16)(v1.z * ct.z - v2.z * st.z);  o2[2] = (_Float16)(v1.z * st.z + v2.z * ct.z);
    o1[3] = (_Float16)(v1.w * ct.w - v2.w * st.w);  o2[3] = (_Float16)(v1.w * st.w + v2.w * ct.w);
    _Float16* dst = which ? Kh : Qh;
    int h1 = c4 >> 6, d1 = c4 & 63;
    *(f16x4*)(dst + ((size_t)(b * 8 + h1) * T_N + t) * 64 + d1) = o1;
    *(f16x4*)(dst + ((size_t)(b * 8 + h1 + 4) * T_N + t) * 64 + d1) = o2;
    return;
  }
  bid -= 2048;   // v transpose: 64x64 tiles, 512 blocks
  __shared__ _Float16 vt[64][72];
  const int b = bid >> 8, h = (bid >> 5) & 7, tt = bid & 31;
  const int t0 = tt * 64;
#pragma unroll
  for (int it = 0; it < 16; ++it) {
    int idx = tid + it * 256;
    int tl = idx >> 6, d = idx & 63;
    vt[d][tl] = (_Float16)qkv[(size_t)(b * T_N + t0 + tl) * 1536 + 1024 + h * 64 + d];
  }
  __syncthreads();
#pragma unroll
  for (int it = 0; it < 2; ++it) {
    int idx = tid + it * 256;
    int d = idx >> 3, tc = (idx & 7) * 8;
    *(f16x8*)(Vh + ((size_t)(b * 8 + h) * 64 + d) * T_N + t0 + tc) =
        *(const f16x8*)&vt[d][tc];
  }
}

// ---------------- fused attention: QK^T + softmax + PV + f16 out ----------
// block = 256 thr (4 waves), one (b, h, 32-row tile). Window staged at
// p = t0-64+jr, jr in [0,96): aligned vector loads; valid mask w=j-1-i.
#define RQ 72
#define RK 72
#define RV 104
#define RP 104
#define RO 72

__global__ __launch_bounds__(256, 4) void attn_fused(
    const _Float16* __restrict__ Qh, const _Float16* __restrict__ Kh,
    const _Float16* __restrict__ Vh, _Float16* __restrict__ Aout) {
  __shared__ __align__(16) _Float16 sm[19200];
  __shared__ float pm[2][32];
  __shared__ float ps[2][32];
  _Float16* Ks  = sm;
  _Float16* Qs  = sm + 6912;
  _Float16* VTs = sm + 9216;
  _Float16* Ps  = sm + 15872;
  _Float16* OH  = sm;           // epilogue overlay on Ks region

  const int wgid = blockIdx.x;
  const int orig = (wgid & 7) * 128 + (wgid >> 3);   // XCD swizzle (1024 = 8*128)
  const int tile = orig & 63;
  const int h = (orig >> 6) & 7;
  const int b = orig >> 9;
  const int t0 = tile * 32;
  const int tid = threadIdx.x;
  const size_t bh = (size_t)(b * 8 + h);

  // ---- stage Q (32x64)
  {
    int i = tid >> 3, d8 = (tid & 7) * 8;
    *(f16x8*)(Qs + i * RQ + d8) =
        *(const f16x8*)(Qh + (bh * T_N + t0 + i) * 64 + d8);
  }
  // ---- stage K (96x64), p = t0-64+jr, zero for p<0
#pragma unroll
  for (int itn = 0; itn < 3; ++itn) {
    int c = tid + itn * 256;
    int jr = c >> 3, d8 = (c & 7) * 8;
    int p = t0 - 64 + jr;
    f16x8 o = {};
    if (p >= 0) o = *(const f16x8*)(Kh + (bh * T_N + p) * 64 + d8);
    *(f16x8*)(Ks + jr * RK + d8) = o;
  }
  // ---- stage VT (64 d x 96 j) from transposed Vh: contiguous & aligned
#pragma unroll
  for (int itn = 0; itn < 3; ++itn) {
    int c = tid + itn * 256;
    int d = c & 63, ci = c >> 6 + 0;
    ci = (c >> 6);
    int jr8 = ci * 8;
    int p8 = t0 - 64 + jr8;
    f16x8 o = {};
    if (p8 >= 0) o = *(const f16x8*)(Vh + (bh * 64 + d) * T_N + p8);
    *(f16x8*)(VTs + d * RV + jr8) = o;
  }
  __syncthreads();

  // ---- wave roles
  const int lane = tid & 63;
  const int il = lane & 15, g = lane >> 4;
  const int w = tid >> 6;
  const int it = w & 1, jh = w >> 1;
  const int i_q = 16 * it + il;

  // QK^T (swapped): sacc[jt][r] = S^T[j][i_q], j = 16*(3jh+jt)+4g+r
  f32x4 sacc[3] = {};
  {
    f16x8 qf0 = *(const f16x8*)(Qs + i_q * RQ + 8 * g);
    f16x8 qf1 = *(const f16x8*)(Qs + i_q * RQ + 32 + 8 * g);
#pragma unroll
    for (int jt = 0; jt < 3; ++jt) {
      int jrow = 16 * (3 * jh + jt) + il;
      f16x8 a0 = *(const f16x8*)(Ks + jrow * RK + 8 * g);
      f16x8 a1 = *(const f16x8*)(Ks + jrow * RK + 32 + 8 * g);
      sacc[jt] = __builtin_amdgcn_mfma_f32_16x16x32_f16(a0, qf0, sacc[jt], 0, 0, 0);
      sacc[jt] = __builtin_amdgcn_mfma_f32_16x16x32_f16(a1, qf1, sacc[jt], 0, 0, 0);
    }
  }
  // ---- softmax across 2 j-halves via LDS partials; valid w = j-1-i in [0,64)
  float mx = -3e38f;
#pragma unroll
  for (int jt = 0; jt < 3; ++jt)
#pragma unroll
    for (int r = 0; r < 4; ++r) {
      int j = 16 * (3 * jh + jt) + 4 * g + r;
      int wv = j - 1 - i_q;
      if (wv >= 0 && wv < 64) mx = fmaxf(mx, sacc[jt][r]);
    }
  mx = fmaxf(mx, __shfl_xor(mx, 16));
  mx = fmaxf(mx, __shfl_xor(mx, 32));
  if (g == 0) pm[jh][i_q] = mx;
  __syncthreads();
  {
    const float m = fmaxf(pm[0][i_q], pm[1][i_q]);
    float sum = 0.f;
#pragma unroll
    for (int jt = 0; jt < 3; ++jt)
#pragma unroll
      for (int r = 0; r < 4; ++r) {
        int j = 16 * (3 * jh + jt) + 4 * g + r;
        int wv = j - 1 - i_q;
        float ex = 0.f;
        if (wv >= 0 && wv < 64) {
          ex = exp2f((sacc[jt][r] - m) * 0.18033688011112042f);  // *0.125*log2(e)
          sum += ex;
        }
        Ps[i_q * RP + j] = (_Float16)ex;
      }
    sum += __shfl_xor(sum, 16);
    sum += __shfl_xor(sum, 32);
    if (g == 0) ps[jh][i_q] = sum;
  }
  __syncthreads();

  // ---- PV: out[i][d] = sum_j P[i][j] * VT[d][j]
  f32x4 oacc[2] = {};
#pragma unroll
  for (int ks = 0; ks < 3; ++ks) {
    f16x8 pf = *(const f16x8*)(Ps + i_q * RP + 32 * ks + 8 * g);
#pragma unroll
    for (int q2 = 0; q2 < 2; ++q2) {
      int dt = jh + 2 * q2;
      f16x8 vf = *(const f16x8*)(VTs + (16 * dt + il) * RV + 32 * ks + 8 * g);
      oacc[q2] = __builtin_amdgcn_mfma_f32_16x16x32_f16(pf, vf, oacc[q2], 0, 0, 0);
    }
  }
  // ---- epilogue: normalize, f16 plane in LDS, coalesced write
#pragma unroll
  for (int r = 0; r < 4; ++r) {
    int i = 16 * it + 4 * g + r;
    float inv = 1.f / (ps[0][i] + ps[1][i]);
#pragma unroll
    for (int q2 = 0; q2 < 2; ++q2) {
      int d = 16 * (jh + 2 * q2) + il;
      OH[i * RO + d] = (_Float16)(oacc[q2][r] * inv);
    }
  }
  __syncthreads();
  {
    int i = tid >> 3, d8 = (tid & 7) * 8;
    *(f16x8*)(Aout + ((size_t)(b * T_N + t0 + i)) * 512 + h * 64 + d8) =
        *(const f16x8*)(OH + i * RO + d8);
  }
}

// ---------------- launch ---------------------------------------------------
extern "C" void kernel_launch(void* const* d_in, const int* in_sizes, int n_in,
                              void* d_out, int out_size, void* d_ws, size_t ws_size,
                              hipStream_t stream) {
  const float* x    = (const float*)d_in[0];
  const float* Wq   = (const float*)d_in[1];
  const float* Wkv  = (const float*)d_in[2];
  const float* Wlin = (const float*)d_in[3];
  const float* blin = (const float*)d_in[4];
  float* out = (float*)d_out;

  char* ws = (char*)d_ws;
  float*     qkvbuf = (float*)(ws);                     // 4096*1536*4 = 25165824
  float*     tab    = (float*)(ws + 25165824);          // 2048*512*4  =  4194304
  _Float16*  Axp    = (_Float16*)(ws + 29360128);       // 4096*512*2  =  4194304
  _Float16*  Wcatp  = (_Float16*)(ws + 33554432);       // 1536*512*2  =  1572864
  _Float16*  Wlinp  = (_Float16*)(ws + 35127296);       //  512*512*2  =   524288
  _Float16*  Qh     = (_Float16*)(ws + 35651584);       // 2*8*2048*64*2 = 4194304
  _Float16*  Kh     = (_Float16*)(ws + 39845888);       // 4194304
  _Float16*  Vh     = (_Float16*)(ws + 44040192);       // 4194304
  _Float16*  Aaop   = (_Float16*)(ws + 48234496);       // 4194304 -> 52428800 total

  trig_kernel<<<T_N, 256, 0, stream>>>(tab);
  pack_all<<<1280, 256, 0, stream>>>(x, Wq, Wkv, Wlin, Axp, Wcatp, Wlinp);
  gemm_mfma<<<dim3(12, 32), 256, 0, stream>>>(Axp, Wcatp, qkvbuf, 1536, nullptr);
  rope_pack<<<2560, 256, 0, stream>>>(qkvbuf, tab, Qh, Kh, Vh);
  attn_fused<<<1024, 256, 0, stream>>>(Qh, Kh, Vh, Aaop);
  gemm_mfma<<<dim3(4, 32), 256, 0, stream>>>(Aaop, Wlinp, out, 512, blin);
}

// Round 6
// 111.979 us; speedup vs baseline: 2.3532x; 1.0377x over previous
//
#include <hip/hip_runtime.h>
#include <cstddef>

#define T_N 2048
#define M_N 4096   // B*T
#define KW  512    // GEMM K

typedef __attribute__((ext_vector_type(4))) float f32x4;
typedef _Float16 f16x8 __attribute__((ext_vector_type(8)));
typedef _Float16 f16x2 __attribute__((ext_vector_type(2)));

#define GLOAD_LDS(g, l) __builtin_amdgcn_global_load_lds( \
    (const __attribute__((address_space(1))) unsigned int*)(g), \
    (__attribute__((address_space(3))) unsigned int*)(l), 16, 0, 0)

// ---------------- prep: x->f16, W's packed/permuted f16, trig f16x2 -------
// blocks [0,1024): x pack; [1024,1280): W packs; [1280,3328): trig table
__global__ __launch_bounds__(256) void prep(
    const float* __restrict__ x, const float* __restrict__ Wq,
    const float* __restrict__ Wkv, const float* __restrict__ Wlin,
    _Float16* __restrict__ Axp, _Float16* __restrict__ Wcatp,
    _Float16* __restrict__ Wlinp, _Float16* __restrict__ tab16) {
  __shared__ float tile[64][65];
  const int bid = blockIdx.x;
  const int tid = threadIdx.x;
  if (bid < 1024) {
    // x [M][512] f32 -> Axp [M][512] f16
    int idx = bid * 256 + tid;           // M*64 ids
    int m = idx >> 6, k8 = (idx & 63) << 3;
    const float* src = x + (size_t)m * 512 + k8;
    const float4 a = *(const float4*)src;
    const float4 b = *(const float4*)(src + 4);
    f16x8 o;
    o[0] = (_Float16)a.x; o[1] = (_Float16)a.y; o[2] = (_Float16)a.z; o[3] = (_Float16)a.w;
    o[4] = (_Float16)b.x; o[5] = (_Float16)b.y; o[6] = (_Float16)b.z; o[7] = (_Float16)b.w;
    *(f16x8*)(Axp + (size_t)m * 512 + k8) = o;
    return;
  }
  if (bid >= 1280) {
    // trig: tab16[t*256+f] = {cos, sin} f16 pair
    int gid = (bid - 1280) * 256 + tid;  // T*256 ids
    int t = gid >> 8, f = gid & 255;
    float invf = exp2f(-0.05190512648261503f * (float)f);  // 10000^(-f/256)
    float s, c;
    sincosf((float)t * invf, &s, &c);
    f16x2 cs;
    cs[0] = (_Float16)c; cs[1] = (_Float16)s;
    *(f16x2*)(tab16 + 2 * ((size_t)t * 256 + f)) = cs;
    return;
  }
  // W packs: transposed, q/k columns pair-interleaved (n' = 2f + p)
  int wb = bid - 1024;
  const float* W; int N; int mode; int bx, by;
  if (wb < 64)       { W = Wq;   N = 512;  mode = 0; bx = wb & 7;  by = wb >> 3; }
  else if (wb < 192) { wb -= 64;  W = Wkv; N = 1024; mode = 1; bx = wb & 15; by = wb >> 4; }
  else               { wb -= 192; W = Wlin; N = 512; mode = 2; bx = wb & 7;  by = wb >> 3; }
  const int n0 = bx * 64, k0 = by * 64;
#pragma unroll
  for (int it = 0; it < 16; ++it) {
    int idx = tid + it * 256;
    int r = idx >> 6, c = idx & 63;
    tile[r][c] = W[(size_t)(k0 + r) * N + n0 + c];
  }
  __syncthreads();
#pragma unroll
  for (int it = 0; it < 16; ++it) {
    int idx = tid + it * 256;
    int n = idx >> 6, kk = idx & 63;
    int cg = n0 + n;
    int np; _Float16* out;
    if (mode == 0)      { np = 2 * (cg & 255) + (cg >> 8); out = Wcatp; }
    else if (mode == 1) { np = (cg < 512) ? 512 + 2 * (cg & 255) + (cg >> 8)
                                          : 1024 + (cg - 512);
                          out = Wcatp; }
    else                { np = cg; out = Wlinp; }
    out[(size_t)np * KW + k0 + kk] = (_Float16)tile[kk][n];
  }
}

// ---------------- qkv GEMM + fused RoPE epilogue --------------------------
// tile 64(M) x 128(N), 4 waves (2x2), K=512. Writes Qh/Kh [b,h,t,64] f16
// (RoPE'd via paired-column + shfl_xor(1)) and Vn [m][512] f16.
__global__ __launch_bounds__(256) void gemm_qkv_rope(
    const _Float16* __restrict__ Ap, const _Float16* __restrict__ Bp,
    const _Float16* __restrict__ tab16, _Float16* __restrict__ Qh,
    _Float16* __restrict__ Kh, _Float16* __restrict__ Vn) {
  __shared__ __align__(16) _Float16 sA[64 * 64];
  __shared__ __align__(16) _Float16 sB[128 * 64];
  const int tid = threadIdx.x;
  const int wid = tid >> 6, lane = tid & 63;
  const int il = lane & 15, g = lane >> 4;
  const int m0 = blockIdx.y * 64, n0 = blockIdx.x * 128;
  const int wm = (wid >> 1) * 32, wn = (wid & 1) * 64;
  f32x4 acc[2][4] = {};

  const _Float16* ga = Ap + (size_t)(m0 + wid * 16 + (lane >> 3)) * KW + (lane & 7) * 8;
  const _Float16* gb = Bp + (size_t)(n0 + wid * 32 + (lane >> 3)) * KW + (lane & 7) * 8;
  _Float16* la = sA + wid * 16 * 64;
  _Float16* lb = sB + wid * 32 * 64;

  for (int k0 = 0; k0 < KW; k0 += 64) {
    GLOAD_LDS(ga + k0, la);
    GLOAD_LDS(ga + 8 * KW + k0, la + 8 * 64);
#pragma unroll
    for (int p = 0; p < 4; ++p)
      GLOAD_LDS(gb + (size_t)(p * 8) * KW + k0, lb + p * 8 * 64);
    __syncthreads();
#pragma unroll
    for (int ks = 0; ks < 2; ++ks) {
      f16x8 af[2], bf[4];
#pragma unroll
      for (int i = 0; i < 2; ++i)
        af[i] = *(const f16x8*)&sA[(wm + i * 16 + il) * 64 + ks * 32 + g * 8];
#pragma unroll
      for (int j = 0; j < 4; ++j)
        bf[j] = *(const f16x8*)&sB[(wn + j * 16 + il) * 64 + ks * 32 + g * 8];
#pragma unroll
      for (int i = 0; i < 2; ++i)
#pragma unroll
        for (int j = 0; j < 4; ++j)
          acc[i][j] = __builtin_amdgcn_mfma_f32_16x16x32_f16(af[i], bf[j], acc[i][j], 0, 0, 0);
    }
    __syncthreads();
  }
  // epilogue: C/D layout col=il (N side), row=g*4+r (M side)  [verified]
  const int b8 = (m0 >> 11) * 8;
  const bool isv = (n0 >= 1024);
  const bool isk = (n0 >= 512) && !isv;
  const int n0p = n0 - (isk ? 512 : 0);
#pragma unroll
  for (int i = 0; i < 2; ++i) {
#pragma unroll
    for (int j = 0; j < 4; ++j) {
      f32x4 v = acc[i][j];
#pragma unroll
      for (int r = 0; r < 4; ++r) {
        float self = v[r];
        float part = __shfl_xor(self, 1);
        int tl = wm + i * 16 + g * 4 + r;
        int tpos = (m0 + tl) & (T_N - 1);
        if (isv) {
          Vn[(size_t)(m0 + tl) * 512 + (n0 - 1024) + wn + il + 16 * j] = (_Float16)self;
        } else {
          int p = il & 1;
          int f = (n0p + wn + 16 * j + (il & 14)) >> 1;  // freq in [0,256)
          f16x2 cs = *(const f16x2*)(tab16 + 2 * ((size_t)tpos * 256 + f));
          float c = (float)cs[0], s = (float)cs[1];
          float o = p ? (self * c + part * s) : (self * c - part * s);
          int h = (f >> 6) + (p << 2);
          int d = f & 63;
          _Float16* dst = isk ? Kh : Qh;
          dst[((size_t)(b8 + h) * T_N + tpos) * 64 + d] = (_Float16)o;
        }
      }
    }
  }
}

// ---------------- V transpose: Vn [m][512] -> Vh [b][h][64][T] ------------
__global__ __launch_bounds__(256) void vtrans(
    const _Float16* __restrict__ Vn, _Float16* __restrict__ Vh) {
  __shared__ _Float16 vt[64][72];
  const int bid = blockIdx.x;
  const int tid = threadIdx.x;
  const int b = bid >> 8, h = (bid >> 5) & 7, tt = bid & 31;
  const int t0 = tt * 64;
#pragma unroll
  for (int it = 0; it < 16; ++it) {
    int idx = tid + it * 256;
    int tl = idx >> 6, d = idx & 63;
    vt[d][tl] = Vn[(size_t)(b * T_N + t0 + tl) * 512 + h * 64 + d];
  }
  __syncthreads();
#pragma unroll
  for (int it = 0; it < 2; ++it) {
    int idx = tid + it * 256;
    int d = idx >> 3, tc = (idx & 7) * 8;
    *(f16x8*)(Vh + ((size_t)(b * 8 + h) * 64 + d) * T_N + t0 + tc) =
        *(const f16x8*)&vt[d][tc];
  }
}

// ---------------- fused attention: QK^T + softmax + PV + f16 out ----------
#define RQ 72
#define RK 72
#define RV 104
#define RP 104
#define RO 72

__global__ __launch_bounds__(256, 4) void attn_fused(
    const _Float16* __restrict__ Qh, const _Float16* __restrict__ Kh,
    const _Float16* __restrict__ Vh, _Float16* __restrict__ Aout) {
  __shared__ __align__(16) _Float16 sm[19200];
  __shared__ float pm[2][32];
  __shared__ float ps[2][32];
  _Float16* Ks  = sm;
  _Float16* Qs  = sm + 6912;
  _Float16* VTs = sm + 9216;
  _Float16* Ps  = sm + 15872;
  _Float16* OH  = sm;           // epilogue overlay on Ks region

  const int wgid = blockIdx.x;
  const int orig = (wgid & 7) * 128 + (wgid >> 3);   // XCD swizzle (1024 = 8*128)
  const int tile = orig & 63;
  const int h = (orig >> 6) & 7;
  const int b = orig >> 9;
  const int t0 = tile * 32;
  const int tid = threadIdx.x;
  const size_t bh = (size_t)(b * 8 + h);

  // ---- stage Q (32x64)
  {
    int i = tid >> 3, d8 = (tid & 7) * 8;
    *(f16x8*)(Qs + i * RQ + d8) =
        *(const f16x8*)(Qh + (bh * T_N + t0 + i) * 64 + d8);
  }
  // ---- stage K (96x64), p = t0-64+jr, zero for p<0
#pragma unroll
  for (int itn = 0; itn < 3; ++itn) {
    int c = tid + itn * 256;
    int jr = c >> 3, d8 = (c & 7) * 8;
    int p = t0 - 64 + jr;
    f16x8 o = {};
    if (p >= 0) o = *(const f16x8*)(Kh + (bh * T_N + p) * 64 + d8);
    *(f16x8*)(Ks + jr * RK + d8) = o;
  }
  // ---- stage VT (64 d x 96 j) from transposed Vh
#pragma unroll
  for (int itn = 0; itn < 3; ++itn) {
    int c = tid + itn * 256;
    int d = c & 63, jr8 = (c >> 6) * 8;
    int p8 = t0 - 64 + jr8;
    f16x8 o = {};
    if (p8 >= 0) o = *(const f16x8*)(Vh + (bh * 64 + d) * T_N + p8);
    *(f16x8*)(VTs + d * RV + jr8) = o;
  }
  __syncthreads();

  // ---- wave roles
  const int lane = tid & 63;
  const int il = lane & 15, g = lane >> 4;
  const int w = tid >> 6;
  const int it = w & 1, jh = w >> 1;
  const int i_q = 16 * it + il;

  // QK^T (swapped): sacc[jt][r] = S^T[j][i_q], j = 16*(3jh+jt)+4g+r
  f32x4 sacc[3] = {};
  {
    f16x8 qf0 = *(const f16x8*)(Qs + i_q * RQ + 8 * g);
    f16x8 qf1 = *(const f16x8*)(Qs + i_q * RQ + 32 + 8 * g);
#pragma unroll
    for (int jt = 0; jt < 3; ++jt) {
      int jrow = 16 * (3 * jh + jt) + il;
      f16x8 a0 = *(const f16x8*)(Ks + jrow * RK + 8 * g);
      f16x8 a1 = *(const f16x8*)(Ks + jrow * RK + 32 + 8 * g);
      sacc[jt] = __builtin_amdgcn_mfma_f32_16x16x32_f16(a0, qf0, sacc[jt], 0, 0, 0);
      sacc[jt] = __builtin_amdgcn_mfma_f32_16x16x32_f16(a1, qf1, sacc[jt], 0, 0, 0);
    }
  }
  // ---- softmax across 2 j-halves via LDS partials; valid w = j-1-i in [0,64)
  float mx = -3e38f;
#pragma unroll
  for (int jt = 0; jt < 3; ++jt)
#pragma unroll
    for (int r = 0; r < 4; ++r) {
      int j = 16 * (3 * jh + jt) + 4 * g + r;
      int wv = j - 1 - i_q;
      if (wv >= 0 && wv < 64) mx = fmaxf(mx, sacc[jt][r]);
    }
  mx = fmaxf(mx, __shfl_xor(mx, 16));
  mx = fmaxf(mx, __shfl_xor(mx, 32));
  if (g == 0) pm[jh][i_q] = mx;
  __syncthreads();
  {
    const float m = fmaxf(pm[0][i_q], pm[1][i_q]);
    float sum = 0.f;
#pragma unroll
    for (int jt = 0; jt < 3; ++jt)
#pragma unroll
      for (int r = 0; r < 4; ++r) {
        int j = 16 * (3 * jh + jt) + 4 * g + r;
        int wv = j - 1 - i_q;
        float ex = 0.f;
        if (wv >= 0 && wv < 64) {
          ex = exp2f((sacc[jt][r] - m) * 0.18033688011112042f);  // *0.125*log2(e)
          sum += ex;
        }
        Ps[i_q * RP + j] = (_Float16)ex;
      }
    sum += __shfl_xor(sum, 16);
    sum += __shfl_xor(sum, 32);
    if (g == 0) ps[jh][i_q] = sum;
  }
  __syncthreads();

  // ---- PV: out[i][d] = sum_j P[i][j] * VT[d][j]
  f32x4 oacc[2] = {};
#pragma unroll
  for (int ks = 0; ks < 3; ++ks) {
    f16x8 pf = *(const f16x8*)(Ps + i_q * RP + 32 * ks + 8 * g);
#pragma unroll
    for (int q2 = 0; q2 < 2; ++q2) {
      int dt = jh + 2 * q2;
      f16x8 vf = *(const f16x8*)(VTs + (16 * dt + il) * RV + 32 * ks + 8 * g);
      oacc[q2] = __builtin_amdgcn_mfma_f32_16x16x32_f16(pf, vf, oacc[q2], 0, 0, 0);
    }
  }
  // ---- epilogue: normalize, f16 plane in LDS, coalesced write
#pragma unroll
  for (int r = 0; r < 4; ++r) {
    int i = 16 * it + 4 * g + r;
    float inv = 1.f / (ps[0][i] + ps[1][i]);
#pragma unroll
    for (int q2 = 0; q2 < 2; ++q2) {
      int d = 16 * (jh + 2 * q2) + il;
      OH[i * RO + d] = (_Float16)(oacc[q2][r] * inv);
    }
  }
  __syncthreads();
  {
    int i = tid >> 3, d8 = (tid & 7) * 8;
    *(f16x8*)(Aout + ((size_t)(b * T_N + t0 + i)) * 512 + h * 64 + d8) =
        *(const f16x8*)(OH + i * RO + d8);
  }
}

// ---------------- output GEMM: out = Aaop @ Wlinp^T + blin ----------------
// tile 64x64, 4 waves (2x2), K=512, f32 out + bias
__global__ __launch_bounds__(256) void gemm_out(
    const _Float16* __restrict__ Ap, const _Float16* __restrict__ Bp,
    const float* __restrict__ bias, float* __restrict__ C) {
  __shared__ __align__(16) _Float16 sA[64 * 64];
  __shared__ __align__(16) _Float16 sB[64 * 64];
  const int tid = threadIdx.x;
  const int wid = tid >> 6, lane = tid & 63;
  const int il = lane & 15, g = lane >> 4;
  const int m0 = blockIdx.y * 64, n0 = blockIdx.x * 64;
  const int wm = (wid >> 1) * 32, wn = (wid & 1) * 32;
  f32x4 acc[2][2] = {};

  const _Float16* ga = Ap + (size_t)(m0 + wid * 16 + (lane >> 3)) * KW + (lane & 7) * 8;
  const _Float16* gb = Bp + (size_t)(n0 + wid * 16 + (lane >> 3)) * KW + (lane & 7) * 8;
  _Float16* la = sA + wid * 16 * 64;
  _Float16* lb = sB + wid * 16 * 64;

  for (int k0 = 0; k0 < KW; k0 += 64) {
    GLOAD_LDS(ga + k0, la);
    GLOAD_LDS(ga + 8 * KW + k0, la + 8 * 64);
    GLOAD_LDS(gb + k0, lb);
    GLOAD_LDS(gb + 8 * KW + k0, lb + 8 * 64);
    __syncthreads();
#pragma unroll
    for (int ks = 0; ks < 2; ++ks) {
      f16x8 af[2], bf[2];
#pragma unroll
      for (int i = 0; i < 2; ++i)
        af[i] = *(const f16x8*)&sA[(wm + i * 16 + il) * 64 + ks * 32 + g * 8];
#pragma unroll
      for (int j = 0; j < 2; ++j)
        bf[j] = *(const f16x8*)&sB[(wn + j * 16 + il) * 64 + ks * 32 + g * 8];
#pragma unroll
      for (int i = 0; i < 2; ++i)
#pragma unroll
        for (int j = 0; j < 2; ++j)
          acc[i][j] = __builtin_amdgcn_mfma_f32_16x16x32_f16(af[i], bf[j], acc[i][j], 0, 0, 0);
    }
    __syncthreads();
  }
  const int cn = n0 + wn + il;
  const int rbase = m0 + wm + g * 4;
#pragma unroll
  for (int j = 0; j < 2; ++j) {
    float badd = bias[cn + j * 16];
#pragma unroll
    for (int i = 0; i < 2; ++i)
#pragma unroll
      for (int r = 0; r < 4; ++r)
        C[(size_t)(rbase + i * 16 + r) * 512 + cn + j * 16] = acc[i][j][r] + badd;
  }
}

// ---------------- launch ---------------------------------------------------
extern "C" void kernel_launch(void* const* d_in, const int* in_sizes, int n_in,
                              void* d_out, int out_size, void* d_ws, size_t ws_size,
                              hipStream_t stream) {
  const float* x    = (const float*)d_in[0];
  const float* Wq   = (const float*)d_in[1];
  const float* Wkv  = (const float*)d_in[2];
  const float* Wlin = (const float*)d_in[3];
  const float* blin = (const float*)d_in[4];
  float* out = (float*)d_out;

  char* ws = (char*)d_ws;
  _Float16* Axp   = (_Float16*)(ws);              // 4096*512*2   = 4194304
  _Float16* Wcatp = (_Float16*)(ws + 4194304);    // 1536*512*2   = 1572864
  _Float16* Wlinp = (_Float16*)(ws + 5767168);    //  512*512*2   =  524288
  _Float16* tab16 = (_Float16*)(ws + 6291456);    // 2048*256*4   = 2097152
  _Float16* Qh    = (_Float16*)(ws + 8388608);    // 16*2048*64*2 = 4194304
  _Float16* Kh    = (_Float16*)(ws + 12582912);   // 4194304
  _Float16* Vn    = (_Float16*)(ws + 16777216);   // 4194304
  _Float16* Vh    = (_Float16*)(ws + 20971520);   // 4194304
  _Float16* Aaop  = (_Float16*)(ws + 25165824);   // 4194304 (end 29360128)

  prep<<<3328, 256, 0, stream>>>(x, Wq, Wkv, Wlin, Axp, Wcatp, Wlinp, tab16);
  gemm_qkv_rope<<<dim3(12, 64), 256, 0, stream>>>(Axp, Wcatp, tab16, Qh, Kh, Vn);
  vtrans<<<512, 256, 0, stream>>>(Vn, Vh);
  attn_fused<<<1024, 256, 0, stream>>>(Qh, Kh, Vh, Aaop);
  gemm_out<<<dim3(8, 64), 256, 0, stream>>>(Aaop, Wlinp, blin, out);
}

// Round 7
// 104.053 us; speedup vs baseline: 2.5324x; 1.0762x over previous
//
#include <hip/hip_runtime.h>
#include <cstddef>

#define T_N 2048
#define M_N 4096   // B*T
#define KW  512    // GEMM K

typedef __attribute__((ext_vector_type(4))) float f32x4;
typedef _Float16 f16x8 __attribute__((ext_vector_type(8)));
typedef _Float16 f16x2 __attribute__((ext_vector_type(2)));

#define GLOAD_LDS(g, l) __builtin_amdgcn_global_load_lds( \
    (const __attribute__((address_space(1))) unsigned int*)(g), \
    (__attribute__((address_space(3))) unsigned int*)(l), 16, 0, 0)

// ---------------- prep: x->f16, W's packed/permuted f16, trig f16x2 -------
// blocks [0,1024): x pack; [1024,1280): W packs; [1280,3328): trig table
__global__ __launch_bounds__(256) void prep(
    const float* __restrict__ x, const float* __restrict__ Wq,
    const float* __restrict__ Wkv, const float* __restrict__ Wlin,
    _Float16* __restrict__ Axp, _Float16* __restrict__ Wcatp,
    _Float16* __restrict__ Wlinp, _Float16* __restrict__ tab16) {
  __shared__ float tile[64][65];
  const int bid = blockIdx.x;
  const int tid = threadIdx.x;
  if (bid < 1024) {
    int idx = bid * 256 + tid;           // M*64 ids
    int m = idx >> 6, k8 = (idx & 63) << 3;
    const float* src = x + (size_t)m * 512 + k8;
    const float4 a = *(const float4*)src;
    const float4 b = *(const float4*)(src + 4);
    f16x8 o;
    o[0] = (_Float16)a.x; o[1] = (_Float16)a.y; o[2] = (_Float16)a.z; o[3] = (_Float16)a.w;
    o[4] = (_Float16)b.x; o[5] = (_Float16)b.y; o[6] = (_Float16)b.z; o[7] = (_Float16)b.w;
    *(f16x8*)(Axp + (size_t)m * 512 + k8) = o;
    return;
  }
  if (bid >= 1280) {
    int gid = (bid - 1280) * 256 + tid;  // T*256 ids
    int t = gid >> 8, f = gid & 255;
    float invf = exp2f(-0.05190512648261503f * (float)f);  // 10000^(-f/256)
    float s, c;
    sincosf((float)t * invf, &s, &c);
    f16x2 cs;
    cs[0] = (_Float16)c; cs[1] = (_Float16)s;
    *(f16x2*)(tab16 + 2 * ((size_t)t * 256 + f)) = cs;
    return;
  }
  int wb = bid - 1024;
  const float* W; int N; int mode; int bx, by;
  if (wb < 64)       { W = Wq;   N = 512;  mode = 0; bx = wb & 7;  by = wb >> 3; }
  else if (wb < 192) { wb -= 64;  W = Wkv; N = 1024; mode = 1; bx = wb & 15; by = wb >> 4; }
  else               { wb -= 192; W = Wlin; N = 512; mode = 2; bx = wb & 7;  by = wb >> 3; }
  const int n0 = bx * 64, k0 = by * 64;
#pragma unroll
  for (int it = 0; it < 16; ++it) {
    int idx = tid + it * 256;
    int r = idx >> 6, c = idx & 63;
    tile[r][c] = W[(size_t)(k0 + r) * N + n0 + c];
  }
  __syncthreads();
#pragma unroll
  for (int it = 0; it < 16; ++it) {
    int idx = tid + it * 256;
    int n = idx >> 6, kk = idx & 63;
    int cg = n0 + n;
    int np; _Float16* out;
    if (mode == 0)      { np = 2 * (cg & 255) + (cg >> 8); out = Wcatp; }
    else if (mode == 1) { np = (cg < 512) ? 512 + 2 * (cg & 255) + (cg >> 8)
                                          : 1024 + (cg - 512);
                          out = Wcatp; }
    else                { np = cg; out = Wlinp; }
    out[(size_t)np * KW + k0 + kk] = (_Float16)tile[kk][n];
  }
}

// ---------------- qkv GEMM + fused RoPE + coalesced LDS epilogue ----------
// tile 64(M) x 128(N), 4 waves (2x2), K=512.
// Q/K n-tiles: one (h0, h0+4) pair -> OT[p][t][d] -> contiguous planes.
// V n-tiles: OTV[col][t] (transposed) -> Vh [b,h,64,T] directly.
__global__ __launch_bounds__(256) void gemm_qkv_rope(
    const _Float16* __restrict__ Ap, const _Float16* __restrict__ Bp,
    const _Float16* __restrict__ tab16, _Float16* __restrict__ Qh,
    _Float16* __restrict__ Kh, _Float16* __restrict__ Vh) {
  __shared__ __align__(16) _Float16 sm[64 * 64 + 128 * 64];  // 12288 f16
  _Float16* sA = sm;
  _Float16* sB = sm + 64 * 64;
  const int tid = threadIdx.x;
  const int wid = tid >> 6, lane = tid & 63;
  const int il = lane & 15, g = lane >> 4;
  const int m0 = blockIdx.y * 64, n0 = blockIdx.x * 128;
  const int wm = (wid >> 1) * 32, wn = (wid & 1) * 64;
  f32x4 acc[2][4] = {};

  const _Float16* ga = Ap + (size_t)(m0 + wid * 16 + (lane >> 3)) * KW + (lane & 7) * 8;
  const _Float16* gb = Bp + (size_t)(n0 + wid * 32 + (lane >> 3)) * KW + (lane & 7) * 8;
  _Float16* la = sA + wid * 16 * 64;
  _Float16* lb = sB + wid * 32 * 64;

  for (int k0 = 0; k0 < KW; k0 += 64) {
    GLOAD_LDS(ga + k0, la);
    GLOAD_LDS(ga + 8 * KW + k0, la + 8 * 64);
#pragma unroll
    for (int p = 0; p < 4; ++p)
      GLOAD_LDS(gb + (size_t)(p * 8) * KW + k0, lb + p * 8 * 64);
    __syncthreads();
#pragma unroll
    for (int ks = 0; ks < 2; ++ks) {
      f16x8 af[2], bf[4];
#pragma unroll
      for (int i = 0; i < 2; ++i)
        af[i] = *(const f16x8*)&sA[(wm + i * 16 + il) * 64 + ks * 32 + g * 8];
#pragma unroll
      for (int j = 0; j < 4; ++j)
        bf[j] = *(const f16x8*)&sB[(wn + j * 16 + il) * 64 + ks * 32 + g * 8];
#pragma unroll
      for (int i = 0; i < 2; ++i)
#pragma unroll
        for (int j = 0; j < 4; ++j)
          acc[i][j] = __builtin_amdgcn_mfma_f32_16x16x32_f16(af[i], bf[j], acc[i][j], 0, 0, 0);
    }
    __syncthreads();
  }
  // ---- epilogue (C/D layout: col=il on N side, row=g*4+r on M side)
  const int b8 = (m0 >> 11) * 8;
  const int tb = m0 & (T_N - 1);
  const bool isv = (n0 >= 1024);
  const bool isk = (n0 >= 512) && !isv;
  // LDS overlay (sA/sB dead after final k-loop barrier)
  _Float16* OT  = sm;                    // [2][64][72] for q/k
  _Float16* OTV = sm;                    // [128][72]  for v

  if (isv) {
#pragma unroll
    for (int i = 0; i < 2; ++i)
#pragma unroll
      for (int j = 0; j < 4; ++j) {
        f32x4 v = acc[i][j];
        int col = wn + 16 * j + il;
#pragma unroll
        for (int r = 0; r < 4; ++r) {
          int tl = wm + i * 16 + g * 4 + r;
          OTV[col * 72 + tl] = (_Float16)v[r];
        }
      }
    __syncthreads();
    const int cv = n0 - 1024;
#pragma unroll
    for (int it = 0; it < 4; ++it) {
      int c = tid + it * 256;             // 1024 chunks
      int col = c >> 3, t8 = (c & 7) * 8;
      int h = (cv + col) >> 6, d = (cv + col) & 63;
      *(f16x8*)(Vh + ((size_t)(b8 + h) * 64 + d) * T_N + tb + t8) =
          *(const f16x8*)&OTV[col * 72 + t8];
    }
    return;
  }
  const int n0p = n0 - (isk ? 512 : 0);
  const int h0 = n0p >> 7;                // head index base (f>>6 constant)
#pragma unroll
  for (int i = 0; i < 2; ++i) {
#pragma unroll
    for (int j = 0; j < 4; ++j) {
      f32x4 v = acc[i][j];
#pragma unroll
      for (int r = 0; r < 4; ++r) {
        float self = v[r];
        float part = __shfl_xor(self, 1);
        int tl = wm + i * 16 + g * 4 + r;
        int tpos = tb + tl;
        int p = il & 1;
        int f = (n0p + wn + 16 * j + (il & 14)) >> 1;   // freq in [64*h0, 64*h0+64)
        f16x2 cs = *(const f16x2*)(tab16 + 2 * ((size_t)tpos * 256 + f));
        float c = (float)cs[0], s = (float)cs[1];
        float o = p ? (self * c + part * s) : (self * c - part * s);
        OT[(p * 64 + tl) * 72 + (f & 63)] = (_Float16)o;
      }
    }
  }
  __syncthreads();
  _Float16* dst = isk ? Kh : Qh;
#pragma unroll
  for (int it = 0; it < 4; ++it) {
    int c = tid + it * 256;               // 1024 chunks: 2 planes x 64 t x 8
    int p = c >> 9, row = (c >> 3) & 63, d8 = (c & 7) * 8;
    *(f16x8*)(dst + ((size_t)(b8 + h0 + 4 * p) * T_N + tb + row) * 64 + d8) =
        *(const f16x8*)&OT[(p * 64 + row) * 72 + d8];
  }
}

// ---------------- fused attention: QK^T + softmax + PV + f16 out ----------
#define RQ 72
#define RK 72
#define RV 104
#define RP 104
#define RO 72

__global__ __launch_bounds__(256, 4) void attn_fused(
    const _Float16* __restrict__ Qh, const _Float16* __restrict__ Kh,
    const _Float16* __restrict__ Vh, _Float16* __restrict__ Aout) {
  __shared__ __align__(16) _Float16 sm[19200];
  __shared__ float pm[2][32];
  __shared__ float ps[2][32];
  _Float16* Ks  = sm;
  _Float16* Qs  = sm + 6912;
  _Float16* VTs = sm + 9216;
  _Float16* Ps  = sm + 15872;
  _Float16* OH  = sm;           // epilogue overlay on Ks region

  const int wgid = blockIdx.x;
  const int orig = (wgid & 7) * 128 + (wgid >> 3);   // XCD swizzle (1024 = 8*128)
  const int tile = orig & 63;
  const int h = (orig >> 6) & 7;
  const int b = orig >> 9;
  const int t0 = tile * 32;
  const int tid = threadIdx.x;
  const size_t bh = (size_t)(b * 8 + h);

  // ---- stage Q (32x64)
  {
    int i = tid >> 3, d8 = (tid & 7) * 8;
    *(f16x8*)(Qs + i * RQ + d8) =
        *(const f16x8*)(Qh + (bh * T_N + t0 + i) * 64 + d8);
  }
  // ---- stage K (96x64), p = t0-64+jr, zero for p<0
#pragma unroll
  for (int itn = 0; itn < 3; ++itn) {
    int c = tid + itn * 256;
    int jr = c >> 3, d8 = (c & 7) * 8;
    int p = t0 - 64 + jr;
    f16x8 o = {};
    if (p >= 0) o = *(const f16x8*)(Kh + (bh * T_N + p) * 64 + d8);
    *(f16x8*)(Ks + jr * RK + d8) = o;
  }
  // ---- stage VT (64 d x 96 j) from transposed Vh
#pragma unroll
  for (int itn = 0; itn < 3; ++itn) {
    int c = tid + itn * 256;
    int d = c & 63, jr8 = (c >> 6) * 8;
    int p8 = t0 - 64 + jr8;
    f16x8 o = {};
    if (p8 >= 0) o = *(const f16x8*)(Vh + (bh * 64 + d) * T_N + p8);
    *(f16x8*)(VTs + d * RV + jr8) = o;
  }
  __syncthreads();

  // ---- wave roles
  const int lane = tid & 63;
  const int il = lane & 15, g = lane >> 4;
  const int w = tid >> 6;
  const int it = w & 1, jh = w >> 1;
  const int i_q = 16 * it + il;

  // QK^T (swapped): sacc[jt][r] = S^T[j][i_q], j = 16*(3jh+jt)+4g+r
  f32x4 sacc[3] = {};
  {
    f16x8 qf0 = *(const f16x8*)(Qs + i_q * RQ + 8 * g);
    f16x8 qf1 = *(const f16x8*)(Qs + i_q * RQ + 32 + 8 * g);
#pragma unroll
    for (int jt = 0; jt < 3; ++jt) {
      int jrow = 16 * (3 * jh + jt) + il;
      f16x8 a0 = *(const f16x8*)(Ks + jrow * RK + 8 * g);
      f16x8 a1 = *(const f16x8*)(Ks + jrow * RK + 32 + 8 * g);
      sacc[jt] = __builtin_amdgcn_mfma_f32_16x16x32_f16(a0, qf0, sacc[jt], 0, 0, 0);
      sacc[jt] = __builtin_amdgcn_mfma_f32_16x16x32_f16(a1, qf1, sacc[jt], 0, 0, 0);
    }
  }
  // ---- softmax across 2 j-halves via LDS partials; valid w = j-1-i in [0,64)
  float mx = -3e38f;
#pragma unroll
  for (int jt = 0; jt < 3; ++jt)
#pragma unroll
    for (int r = 0; r < 4; ++r) {
      int j = 16 * (3 * jh + jt) + 4 * g + r;
      int wv = j - 1 - i_q;
      if (wv >= 0 && wv < 64) mx = fmaxf(mx, sacc[jt][r]);
    }
  mx = fmaxf(mx, __shfl_xor(mx, 16));
  mx = fmaxf(mx, __shfl_xor(mx, 32));
  if (g == 0) pm[jh][i_q] = mx;
  __syncthreads();
  {
    const float m = fmaxf(pm[0][i_q], pm[1][i_q]);
    float sum = 0.f;
#pragma unroll
    for (int jt = 0; jt < 3; ++jt)
#pragma unroll
      for (int r = 0; r < 4; ++r) {
        int j = 16 * (3 * jh + jt) + 4 * g + r;
        int wv = j - 1 - i_q;
        float ex = 0.f;
        if (wv >= 0 && wv < 64) {
          ex = exp2f((sacc[jt][r] - m) * 0.18033688011112042f);  // *0.125*log2(e)
          sum += ex;
        }
        Ps[i_q * RP + j] = (_Float16)ex;
      }
    sum += __shfl_xor(sum, 16);
    sum += __shfl_xor(sum, 32);
    if (g == 0) ps[jh][i_q] = sum;
  }
  __syncthreads();

  // ---- PV: out[i][d] = sum_j P[i][j] * VT[d][j]
  f32x4 oacc[2] = {};
#pragma unroll
  for (int ks = 0; ks < 3; ++ks) {
    f16x8 pf = *(const f16x8*)(Ps + i_q * RP + 32 * ks + 8 * g);
#pragma unroll
    for (int q2 = 0; q2 < 2; ++q2) {
      int dt = jh + 2 * q2;
      f16x8 vf = *(const f16x8*)(VTs + (16 * dt + il) * RV + 32 * ks + 8 * g);
      oacc[q2] = __builtin_amdgcn_mfma_f32_16x16x32_f16(pf, vf, oacc[q2], 0, 0, 0);
    }
  }
  // ---- epilogue: normalize, f16 plane in LDS, coalesced write
#pragma unroll
  for (int r = 0; r < 4; ++r) {
    int i = 16 * it + 4 * g + r;
    float inv = 1.f / (ps[0][i] + ps[1][i]);
#pragma unroll
    for (int q2 = 0; q2 < 2; ++q2) {
      int d = 16 * (jh + 2 * q2) + il;
      OH[i * RO + d] = (_Float16)(oacc[q2][r] * inv);
    }
  }
  __syncthreads();
  {
    int i = tid >> 3, d8 = (tid & 7) * 8;
    *(f16x8*)(Aout + ((size_t)(b * T_N + t0 + i)) * 512 + h * 64 + d8) =
        *(const f16x8*)(OH + i * RO + d8);
  }
}

// ---------------- output GEMM: out = Aaop @ Wlinp^T + blin ----------------
__global__ __launch_bounds__(256) void gemm_out(
    const _Float16* __restrict__ Ap, const _Float16* __restrict__ Bp,
    const float* __restrict__ bias, float* __restrict__ C) {
  __shared__ __align__(16) _Float16 sA[64 * 64];
  __shared__ __align__(16) _Float16 sB[64 * 64];
  const int tid = threadIdx.x;
  const int wid = tid >> 6, lane = tid & 63;
  const int il = lane & 15, g = lane >> 4;
  const int m0 = blockIdx.y * 64, n0 = blockIdx.x * 64;
  const int wm = (wid >> 1) * 32, wn = (wid & 1) * 32;
  f32x4 acc[2][2] = {};

  const _Float16* ga = Ap + (size_t)(m0 + wid * 16 + (lane >> 3)) * KW + (lane & 7) * 8;
  const _Float16* gb = Bp + (size_t)(n0 + wid * 16 + (lane >> 3)) * KW + (lane & 7) * 8;
  _Float16* la = sA + wid * 16 * 64;
  _Float16* lb = sB + wid * 16 * 64;

  for (int k0 = 0; k0 < KW; k0 += 64) {
    GLOAD_LDS(ga + k0, la);
    GLOAD_LDS(ga + 8 * KW + k0, la + 8 * 64);
    GLOAD_LDS(gb + k0, lb);
    GLOAD_LDS(gb + 8 * KW + k0, lb + 8 * 64);
    __syncthreads();
#pragma unroll
    for (int ks = 0; ks < 2; ++ks) {
      f16x8 af[2], bf[2];
#pragma unroll
      for (int i = 0; i < 2; ++i)
        af[i] = *(const f16x8*)&sA[(wm + i * 16 + il) * 64 + ks * 32 + g * 8];
#pragma unroll
      for (int j = 0; j < 2; ++j)
        bf[j] = *(const f16x8*)&sB[(wn + j * 16 + il) * 64 + ks * 32 + g * 8];
#pragma unroll
      for (int i = 0; i < 2; ++i)
#pragma unroll
        for (int j = 0; j < 2; ++j)
          acc[i][j] = __builtin_amdgcn_mfma_f32_16x16x32_f16(af[i], bf[j], acc[i][j], 0, 0, 0);
    }
    __syncthreads();
  }
  const int cn = n0 + wn + il;
  const int rbase = m0 + wm + g * 4;
#pragma unroll
  for (int j = 0; j < 2; ++j) {
    float badd = bias[cn + j * 16];
#pragma unroll
    for (int i = 0; i < 2; ++i)
#pragma unroll
      for (int r = 0; r < 4; ++r)
        C[(size_t)(rbase + i * 16 + r) * 512 + cn + j * 16] = acc[i][j][r] + badd;
  }
}

// ---------------- launch ---------------------------------------------------
extern "C" void kernel_launch(void* const* d_in, const int* in_sizes, int n_in,
                              void* d_out, int out_size, void* d_ws, size_t ws_size,
                              hipStream_t stream) {
  const float* x    = (const float*)d_in[0];
  const float* Wq   = (const float*)d_in[1];
  const float* Wkv  = (const float*)d_in[2];
  const float* Wlin = (const float*)d_in[3];
  const float* blin = (const float*)d_in[4];
  float* out = (float*)d_out;

  char* ws = (char*)d_ws;
  _Float16* Axp   = (_Float16*)(ws);              // 4096*512*2   = 4194304
  _Float16* Wcatp = (_Float16*)(ws + 4194304);    // 1536*512*2   = 1572864
  _Float16* Wlinp = (_Float16*)(ws + 5767168);    //  512*512*2   =  524288
  _Float16* tab16 = (_Float16*)(ws + 6291456);    // 2048*256*4   = 2097152
  _Float16* Qh    = (_Float16*)(ws + 8388608);    // 16*2048*64*2 = 4194304
  _Float16* Kh    = (_Float16*)(ws + 12582912);   // 4194304
  _Float16* Vh    = (_Float16*)(ws + 16777216);   // 4194304
  _Float16* Aaop  = (_Float16*)(ws + 20971520);   // 4194304 (end 25165824)

  prep<<<3328, 256, 0, stream>>>(x, Wq, Wkv, Wlin, Axp, Wcatp, Wlinp, tab16);
  gemm_qkv_rope<<<dim3(12, 64), 256, 0, stream>>>(Axp, Wcatp, tab16, Qh, Kh, Vh);
  attn_fused<<<1024, 256, 0, stream>>>(Qh, Kh, Vh, Aaop);
  gemm_out<<<dim3(8, 64), 256, 0, stream>>>(Aaop, Wlinp, blin, out);
}